// Round 5
// baseline (606.808 us; speedup 1.0000x reference)
//
#include <hip/hip_runtime.h>
#include <math.h>

#define NG 256
#define NPART 8
#define FCH 120   // edge chunks per partition

// ---------------- degree init / norm ----------------
__global__ void zero1(int* deg, int n) {
    int i = blockIdx.x * blockDim.x + threadIdx.x;
    if (i < n) deg[i] = 0;
}

// dst-partitioned histogram: block b owns partition b%8 (XCD-local atomics)
__global__ void histP(const int* __restrict__ dst, int* deg, int e, int n) {
    int p = blockIdx.x & (NPART - 1);
    int chunk = blockIdx.x / NPART;
    int lo = (int)((long long)p * n / NPART);
    int hi = (int)((long long)(p + 1) * n / NPART);
    int i0 = (int)((long long)chunk * e / FCH);
    int i1 = (int)((long long)(chunk + 1) * e / FCH);
    for (int i = i0 + threadIdx.x; i < i1; i += blockDim.x) {
        int d = dst[i];
        if (d >= lo && d < hi) atomicAdd(&deg[d], 1);
    }
}

__global__ void make_dinv(const int* __restrict__ deg, float* dinv, int n) {
    int i = blockIdx.x * blockDim.x + threadIdx.x;
    if (i < n) dinv[i] = rsqrtf((float)deg[i] + 1.0f);  // +1 self-loop
}

// ---------------- exclusive scan of deg -> rowptr ----------------
__global__ void scan_blk(const int* __restrict__ deg, int* rowptr,
                         int* blksum, int n) {
    __shared__ int sh[1024];
    int tid = threadIdx.x;
    int g = blockIdx.x * 1024 + tid;
    int v = (g < n) ? deg[g] : 0;
    sh[tid] = v;
    __syncthreads();
    for (int off = 1; off < 1024; off <<= 1) {
        int t = (tid >= off) ? sh[tid - off] : 0;
        __syncthreads();
        sh[tid] += t;
        __syncthreads();
    }
    if (g < n) rowptr[g + 1] = sh[tid];
    if (tid == 1023) blksum[blockIdx.x] = sh[1023];
}

__global__ void scan_sums(int* blksum, int nb) {
    if (blockIdx.x == 0 && threadIdx.x == 0) {
        int run = 0;
        for (int b = 0; b < nb; ++b) { run += blksum[b]; blksum[b] = run; }
    }
}

__global__ void scan_add(int* rowptr, const int* __restrict__ blksum, int n) {
    int g = blockIdx.x * blockDim.x + threadIdx.x;
    if (g == 0) rowptr[0] = 0;
    if (g < n) {
        int b = g >> 10;
        if (b > 0) rowptr[g + 1] += blksum[b - 1];
    }
}

__global__ void copy_cursor(const int* __restrict__ rowptr, int* cursor, int n) {
    int i = blockIdx.x * blockDim.x + threadIdx.x;
    if (i < n) cursor[i] = rowptr[i];
}

// ------- dst-partitioned CSR fill: partition p's CSR region is written ----
// ------- only by blocks with blockIdx%8==p -> lines merge in one XCD L2 ---
__global__ void fillP(const int* __restrict__ src, const int* __restrict__ dst,
                      const float* __restrict__ dinv, int* cursor,
                      int2* edges, int e, int n) {
    int p = blockIdx.x & (NPART - 1);
    int chunk = blockIdx.x / NPART;
    int lo = (int)((long long)p * n / NPART);
    int hi = (int)((long long)(p + 1) * n / NPART);
    int i0 = (int)((long long)chunk * e / FCH);
    int i1 = (int)((long long)(chunk + 1) * e / FCH);
    for (int i = i0 + threadIdx.x; i < i1; i += blockDim.x) {
        int d = dst[i];
        if (d >= lo && d < hi) {
            int s = src[i];
            int pos = atomicAdd(&cursor[d], 1);
            int2 ed;
            ed.x = s;
            ed.y = __float_as_int(dinv[s] * dinv[d]);
            edges[pos] = ed;
        }
    }
}

// ---------------- layer-1 aggregate on raw x (5-dim), thread = node ------
__global__ void gather5(const int* __restrict__ rowptr,
                        const int2* __restrict__ edges,
                        const float* __restrict__ dinv,
                        const float* __restrict__ x,
                        float* __restrict__ z, int n) {
    int i = blockIdx.x * blockDim.x + threadIdx.x;
    if (i >= n) return;
    float di = dinv[i];
    float ws = di * di;
    const float* xr = x + (size_t)i * 5;
    float4 x4 = *(const float4*)(xr);
    float a0 = x4.x * ws, a1 = x4.y * ws, a2 = x4.z * ws,
          a3 = x4.w * ws, a4 = xr[4] * ws;
    int end = rowptr[i + 1];
    for (int j = rowptr[i]; j < end; ++j) {
        int2 ed = edges[j];
        float w = __int_as_float(ed.y);
        const float* r = x + (size_t)ed.x * 5;
        float4 r4 = *(const float4*)(r);   // 16B + 4B: 2 loads per row
        float r1 = r[4];
        a0 = fmaf(w, r4.x, a0);
        a1 = fmaf(w, r4.y, a1);
        a2 = fmaf(w, r4.z, a2);
        a3 = fmaf(w, r4.w, a3);
        a4 = fmaf(w, r1, a4);
    }
    float* zr = z + (size_t)i * 5;
    zr[0] = a0; zr[1] = a1; zr[2] = a2; zr[3] = a3; zr[4] = a4;
}

// ------- dense transform, 8 outputs x NODES nodes per thread -------------
template<int K, int DOUT, bool BR, int NODES>
__global__ void transformB(const float* __restrict__ xin,
                           const float* __restrict__ W,
                           const float* __restrict__ b,
                           float* __restrict__ out, int n) {
    const int C = DOUT / 8;
    int tid = blockIdx.x * blockDim.x + threadIdx.x;
    int grp = tid / C;
    int c = tid % C;
    int i0 = grp * NODES;
    if (i0 >= n) return;
    float acc[NODES][8];
#pragma unroll
    for (int nn = 0; nn < NODES; ++nn)
#pragma unroll
        for (int q = 0; q < 8; ++q) acc[nn][q] = 0.0f;

    static_assert(K % 4 == 0, "K multiple of 4");
    for (int k0 = 0; k0 < K; k0 += 4) {
        float4 r[NODES];
#pragma unroll
        for (int nn = 0; nn < NODES; ++nn) {
            int idx = i0 + nn < n ? i0 + nn : n - 1;  // clamp (redundant read)
            r[nn] = *(const float4*)(xin + (size_t)idx * K + k0);
        }
#pragma unroll
        for (int kk = 0; kk < 4; ++kk) {
            const float* wp = W + (size_t)(k0 + kk) * DOUT + c * 8;
            float4 w0 = *(const float4*)(wp);
            float4 w1 = *(const float4*)(wp + 4);
#pragma unroll
            for (int nn = 0; nn < NODES; ++nn) {
                float v = (&r[nn].x)[kk];
                acc[nn][0] = fmaf(v, w0.x, acc[nn][0]);
                acc[nn][1] = fmaf(v, w0.y, acc[nn][1]);
                acc[nn][2] = fmaf(v, w0.z, acc[nn][2]);
                acc[nn][3] = fmaf(v, w0.w, acc[nn][3]);
                acc[nn][4] = fmaf(v, w1.x, acc[nn][4]);
                acc[nn][5] = fmaf(v, w1.y, acc[nn][5]);
                acc[nn][6] = fmaf(v, w1.z, acc[nn][6]);
                acc[nn][7] = fmaf(v, w1.w, acc[nn][7]);
            }
        }
    }
    float4 b0, b1;
    if (BR) {
        b0 = *(const float4*)(b + c * 8);
        b1 = *(const float4*)(b + c * 8 + 4);
    }
#pragma unroll
    for (int nn = 0; nn < NODES; ++nn) {
        if (i0 + nn >= n) break;
        float4 o0, o1;
        o0.x = acc[nn][0]; o0.y = acc[nn][1]; o0.z = acc[nn][2]; o0.w = acc[nn][3];
        o1.x = acc[nn][4]; o1.y = acc[nn][5]; o1.z = acc[nn][6]; o1.w = acc[nn][7];
        if (BR) {
            o0.x = fmaxf(o0.x + b0.x, 0.f); o0.y = fmaxf(o0.y + b0.y, 0.f);
            o0.z = fmaxf(o0.z + b0.z, 0.f); o0.w = fmaxf(o0.w + b0.w, 0.f);
            o1.x = fmaxf(o1.x + b1.x, 0.f); o1.y = fmaxf(o1.y + b1.y, 0.f);
            o1.z = fmaxf(o1.z + b1.z, 0.f); o1.w = fmaxf(o1.w + b1.w, 0.f);
        }
        float* op = out + (size_t)(i0 + nn) * DOUT + c * 8;
        *(float4*)(op) = o0;
        *(float4*)(op + 4) = o1;
    }
}

// ---- K=5 variant (layer 1) ---------------------------------------------
template<int DOUT, bool BR, int NODES>
__global__ void transformB5(const float* __restrict__ xin,
                            const float* __restrict__ W,
                            const float* __restrict__ b,
                            float* __restrict__ out, int n) {
    const int C = DOUT / 8;
    int tid = blockIdx.x * blockDim.x + threadIdx.x;
    int grp = tid / C;
    int c = tid % C;
    int i0 = grp * NODES;
    if (i0 >= n) return;
    float r[NODES][5];
#pragma unroll
    for (int nn = 0; nn < NODES; ++nn) {
        int idx = i0 + nn < n ? i0 + nn : n - 1;
        const float* row = xin + (size_t)idx * 5;
#pragma unroll
        for (int k = 0; k < 5; ++k) r[nn][k] = row[k];
    }
    float acc[NODES][8];
#pragma unroll
    for (int nn = 0; nn < NODES; ++nn)
#pragma unroll
        for (int q = 0; q < 8; ++q) acc[nn][q] = 0.0f;
#pragma unroll
    for (int k = 0; k < 5; ++k) {
        const float* wp = W + (size_t)k * DOUT + c * 8;
        float4 w0 = *(const float4*)(wp);
        float4 w1 = *(const float4*)(wp + 4);
#pragma unroll
        for (int nn = 0; nn < NODES; ++nn) {
            float v = r[nn][k];
            acc[nn][0] = fmaf(v, w0.x, acc[nn][0]);
            acc[nn][1] = fmaf(v, w0.y, acc[nn][1]);
            acc[nn][2] = fmaf(v, w0.z, acc[nn][2]);
            acc[nn][3] = fmaf(v, w0.w, acc[nn][3]);
            acc[nn][4] = fmaf(v, w1.x, acc[nn][4]);
            acc[nn][5] = fmaf(v, w1.y, acc[nn][5]);
            acc[nn][6] = fmaf(v, w1.z, acc[nn][6]);
            acc[nn][7] = fmaf(v, w1.w, acc[nn][7]);
        }
    }
    float4 b0, b1;
    if (BR) {
        b0 = *(const float4*)(b + c * 8);
        b1 = *(const float4*)(b + c * 8 + 4);
    }
#pragma unroll
    for (int nn = 0; nn < NODES; ++nn) {
        if (i0 + nn >= n) break;
        float4 o0, o1;
        o0.x = acc[nn][0]; o0.y = acc[nn][1]; o0.z = acc[nn][2]; o0.w = acc[nn][3];
        o1.x = acc[nn][4]; o1.y = acc[nn][5]; o1.z = acc[nn][6]; o1.w = acc[nn][7];
        if (BR) {
            o0.x = fmaxf(o0.x + b0.x, 0.f); o0.y = fmaxf(o0.y + b0.y, 0.f);
            o0.z = fmaxf(o0.z + b0.z, 0.f); o0.w = fmaxf(o0.w + b0.w, 0.f);
            o1.x = fmaxf(o1.x + b1.x, 0.f); o1.y = fmaxf(o1.y + b1.y, 0.f);
            o1.w = fmaxf(o1.w + b1.w, 0.f); o1.z = fmaxf(o1.z + b1.z, 0.f);
        }
        float* op = out + (size_t)(i0 + nn) * DOUT + c * 8;
        *(float4*)(op) = o0;
        *(float4*)(op + 4) = o1;
    }
}

// ------- per-node gather (64-dim): 16 lanes/node, float4 per lane --------
template<bool BR>
__global__ void gather4(const int* __restrict__ rowptr,
                        const int2* __restrict__ edges,
                        const float* __restrict__ dinv,
                        const float* __restrict__ b,
                        const float* __restrict__ t,   // [n][64]
                        float* __restrict__ h, int n) {
    int tid = blockIdx.x * blockDim.x + threadIdx.x;
    int i = tid >> 4;
    int c = tid & 15;
    if (i >= n) return;
    float di = dinv[i];
    float ws = di * di;
    float4 sv = *(const float4*)(t + (size_t)i * 64 + c * 4);
    float4 a0, a1 = {0.f, 0.f, 0.f, 0.f};
    a0.x = sv.x * ws; a0.y = sv.y * ws; a0.z = sv.z * ws; a0.w = sv.w * ws;
    if (BR) {
        float4 bb = *(const float4*)(b + c * 4);
        a0.x += bb.x; a0.y += bb.y; a0.z += bb.z; a0.w += bb.w;
    }
    int j = rowptr[i], end = rowptr[i + 1];
    for (; j + 1 < end; j += 2) {
        int2 e0 = edges[j], e1 = edges[j + 1];
        float w0 = __int_as_float(e0.y), w1 = __int_as_float(e1.y);
        float4 v0 = *(const float4*)(t + (size_t)e0.x * 64 + c * 4);
        float4 v1 = *(const float4*)(t + (size_t)e1.x * 64 + c * 4);
        a0.x = fmaf(w0, v0.x, a0.x); a0.y = fmaf(w0, v0.y, a0.y);
        a0.z = fmaf(w0, v0.z, a0.z); a0.w = fmaf(w0, v0.w, a0.w);
        a1.x = fmaf(w1, v1.x, a1.x); a1.y = fmaf(w1, v1.y, a1.y);
        a1.z = fmaf(w1, v1.z, a1.z); a1.w = fmaf(w1, v1.w, a1.w);
    }
    if (j < end) {
        int2 e0 = edges[j];
        float w0 = __int_as_float(e0.y);
        float4 v0 = *(const float4*)(t + (size_t)e0.x * 64 + c * 4);
        a0.x = fmaf(w0, v0.x, a0.x); a0.y = fmaf(w0, v0.y, a0.y);
        a0.z = fmaf(w0, v0.z, a0.z); a0.w = fmaf(w0, v0.w, a0.w);
    }
    float4 o;
    o.x = a0.x + a1.x; o.y = a0.y + a1.y; o.z = a0.z + a1.z; o.w = a0.w + a1.w;
    if (BR) {
        o.x = fmaxf(o.x, 0.f); o.y = fmaxf(o.y, 0.f);
        o.z = fmaxf(o.z, 0.f); o.w = fmaxf(o.w, 0.f);
    }
    *(float4*)(h + (size_t)i * 64 + c * 4) = o;
}

// ------- pooling + FC + sigmoid: 4 waves per graph, LDS combine ---------
__global__ void pool(const float* __restrict__ h3, const int* __restrict__ batch,
                     const float* __restrict__ Wfc, const float* __restrict__ bfc,
                     float* __restrict__ out, int n) {
    int g = blockIdx.x;
    int lane = threadIdx.x & 63;
    int w = threadIdx.x >> 6;  // 0..3
    int lo = 0, hi = n;
    while (lo < hi) { int m = (lo + hi) >> 1; if (batch[m] < g) lo = m + 1; else hi = m; }
    int start = lo;
    hi = n;
    while (lo < hi) { int m = (lo + hi) >> 1; if (batch[m] < g + 1) lo = m + 1; else hi = m; }
    int end = lo;
    float a0 = 0.f, a1 = 0.f, a2 = 0.f, a3 = 0.f;
    int m = start + w;
    for (; m + 12 < end; m += 16) {
        a0 += h3[(size_t)m * 64 + lane];
        a1 += h3[(size_t)(m + 4) * 64 + lane];
        a2 += h3[(size_t)(m + 8) * 64 + lane];
        a3 += h3[(size_t)(m + 12) * 64 + lane];
    }
    for (; m < end; m += 4) a0 += h3[(size_t)m * 64 + lane];
    __shared__ float sh[4][64];
    sh[w][lane] = (a0 + a1) + (a2 + a3);
    __syncthreads();
    if (w == 0) {
        float v = (sh[0][lane] + sh[1][lane]) + (sh[2][lane] + sh[3][lane]);
        float cnt = (float)(end - start);
        v = (v / fmaxf(cnt, 1.0f)) * Wfc[lane];
#pragma unroll
        for (int off = 32; off > 0; off >>= 1) v += __shfl_down(v, off, 64);
        if (lane == 0) out[g] = 1.0f / (1.0f + expf(-(v + bfc[0])));
    }
}

static inline int cdiv(long long a, int b) { return (int)((a + b - 1) / b); }

extern "C" void kernel_launch(void* const* d_in, const int* in_sizes, int n_in,
                              void* d_out, int out_size, void* d_ws, size_t ws_size,
                              hipStream_t stream) {
    const float* x   = (const float*)d_in[0];
    const int*   ei  = (const int*)d_in[1];
    const int*   bat = (const int*)d_in[2];
    const float* W1  = (const float*)d_in[3];
    const float* b1  = (const float*)d_in[4];
    const float* W2  = (const float*)d_in[5];
    const float* b2  = (const float*)d_in[6];
    const float* W3  = (const float*)d_in[7];
    const float* b3  = (const float*)d_in[8];
    const float* Wfc = (const float*)d_in[9];
    const float* bfc = (const float*)d_in[10];
    float* out = (float*)d_out;

    const int N = in_sizes[0] / 5;   // 100000
    const int E = in_sizes[1] / 2;   // 1600000
    const int* src = ei;
    const int* dst = ei + E;

    // ---- workspace layout ----
    float* ws    = (float*)d_ws;
    float* dinv  = ws;                          // N
    int*   deg   = (int*)(dinv + N);            // N
    int*   rowptr= deg + N;                     // N+4
    int*   cursor= rowptr + N + 4;              // N
    int*   blksum= cursor + N;                  // 128
    int2*  edges = (int2*)(blksum + 128);       // E pairs
    float* A     = (float*)(edges + E);         // N*128
    float* B     = A + (size_t)N * 128;         // N*128

    const int Blk = 256;
    const int NB = cdiv(N, 1024);

    // ---- norm + CSR build (dst-partitioned, XCD-aligned) ----
    zero1<<<cdiv(N, Blk), Blk, 0, stream>>>(deg, N);
    histP<<<NPART * FCH, Blk, 0, stream>>>(dst, deg, E, N);
    make_dinv<<<cdiv(N, Blk), Blk, 0, stream>>>(deg, dinv, N);
    scan_blk<<<NB, 1024, 0, stream>>>(deg, rowptr, blksum, N);
    scan_sums<<<1, 64, 0, stream>>>(blksum, NB);
    scan_add<<<cdiv(N, Blk), Blk, 0, stream>>>(rowptr, blksum, N);
    copy_cursor<<<cdiv(N, Blk), Blk, 0, stream>>>(rowptr, cursor, N);
    fillP<<<NPART * FCH, Blk, 0, stream>>>(src, dst, dinv, cursor, edges, E, N);

    // ---- layer 1: aggregate raw x (5-dim), then 5->64 + relu ----
    gather5<<<cdiv(N, Blk), Blk, 0, stream>>>(rowptr, edges, dinv, x, A, N);
    transformB5<64, true, 4><<<cdiv((long long)cdiv(N, 4) * 8, Blk), Blk, 0, stream>>>(
        A, W1, b1, B, N);                                   // h1 -> B

    // ---- layer 2: aggregate h1 (64-dim), then 64->128 + relu ----
    gather4<false><<<cdiv((long long)N * 16, Blk), Blk, 0, stream>>>(
        rowptr, edges, dinv, nullptr, B, A, N);             // z2 -> A
    transformB<64, 128, true, 8><<<cdiv((long long)cdiv(N, 8) * 16, Blk), Blk, 0, stream>>>(
        A, W2, b2, B, N);                                   // h2 -> B

    // ---- layer 3: 128->64 first, then aggregate + bias + relu ----
    transformB<128, 64, false, 8><<<cdiv((long long)cdiv(N, 8) * 8, Blk), Blk, 0, stream>>>(
        B, W3, nullptr, A, N);                              // t3 -> A
    gather4<true><<<cdiv((long long)N * 16, Blk), Blk, 0, stream>>>(
        rowptr, edges, dinv, b3, A, B, N);                  // h3 -> B

    // ---- pooling + FC head ----
    pool<<<NG, 256, 0, stream>>>(B, bat, Wfc, bfc, out, N);
}

// Round 6
// 526.302 us; speedup vs baseline: 1.1530x; 1.1530x over previous
//
#include <hip/hip_runtime.h>
#include <math.h>

#define NG 256
#define NBK 512          // sort buckets
#define BCAP 3584        // per-bucket staging capacity (mean 3125, +8 sigma)

static __device__ __forceinline__ int bucket_lo(int p, int n) {
    return (int)(((long long)p * n + NBK - 1) / NBK);   // ceil(p*n/NBK)
}

// ---------------- bucket cursor init ----------------
__global__ void zero_bcur(int* bcur) {
    int i = blockIdx.x * blockDim.x + threadIdx.x;
    if (i < NBK) bcur[i] = i * BCAP;
}

// ------- phase A: bucket edges by dst into staged {src,dst} runs --------
__global__ void bucketA(const int* __restrict__ src, const int* __restrict__ dst,
                        int* bcur, int2* stage, int e, int n) {
    __shared__ int cnt[NBK];
    __shared__ int base[NBK];
    int nb = gridDim.x;
    int c0 = (int)((long long)blockIdx.x * e / nb);
    int c1 = (int)((long long)(blockIdx.x + 1) * e / nb);
    for (int k = threadIdx.x; k < NBK; k += blockDim.x) cnt[k] = 0;
    __syncthreads();
    for (int i = c0 + threadIdx.x; i < c1; i += blockDim.x) {
        int d = dst[i];
        int p = (int)((long long)d * NBK / n);
        atomicAdd(&cnt[p], 1);
    }
    __syncthreads();
    for (int k = threadIdx.x; k < NBK; k += blockDim.x)
        base[k] = atomicAdd(&bcur[k], cnt[k]);
    __syncthreads();
    for (int k = threadIdx.x; k < NBK; k += blockDim.x) cnt[k] = 0;
    __syncthreads();
    for (int i = c0 + threadIdx.x; i < c1; i += blockDim.x) {
        int s = src[i], d = dst[i];
        int p = (int)((long long)d * NBK / n);
        int lp = atomicAdd(&cnt[p], 1);
        int2 ed; ed.x = s; ed.y = d;
        stage[base[p] + lp] = ed;     // contiguous per-(block,bucket) runs
    }
}

// ------- per-bucket degree histogram (LDS counters, coalesced write) ----
__global__ void histB(const int2* __restrict__ stage, const int* __restrict__ bcur,
                      int* __restrict__ deg, int n) {
    __shared__ int ldeg[256];
    int p = blockIdx.x;
    int lo = bucket_lo(p, n), hi = bucket_lo(p + 1, n);
    int nloc = hi - lo;                       // <= 196
    for (int k = threadIdx.x; k < nloc; k += blockDim.x) ldeg[k] = 0;
    __syncthreads();
    int s0 = p * BCAP, s1 = bcur[p];
    for (int i = s0 + threadIdx.x; i < s1; i += blockDim.x) {
        int d = stage[i].y;
        atomicAdd(&ldeg[d - lo], 1);
    }
    __syncthreads();
    for (int k = threadIdx.x; k < nloc; k += blockDim.x) deg[lo + k] = ldeg[k];
}

__global__ void make_dinv(const int* __restrict__ deg, float* dinv, int n) {
    int i = blockIdx.x * blockDim.x + threadIdx.x;
    if (i < n) dinv[i] = rsqrtf((float)deg[i] + 1.0f);  // +1 self-loop
}

// ---------------- exclusive scan of deg -> rowptr ----------------
__global__ void scan_blk(const int* __restrict__ deg, int* rowptr,
                         int* blksum, int n) {
    __shared__ int sh[1024];
    int tid = threadIdx.x;
    int g = blockIdx.x * 1024 + tid;
    int v = (g < n) ? deg[g] : 0;
    sh[tid] = v;
    __syncthreads();
    for (int off = 1; off < 1024; off <<= 1) {
        int t = (tid >= off) ? sh[tid - off] : 0;
        __syncthreads();
        sh[tid] += t;
        __syncthreads();
    }
    if (g < n) rowptr[g + 1] = sh[tid];
    if (tid == 1023) blksum[blockIdx.x] = sh[1023];
}

__global__ void scan_sums(int* blksum, int nb) {
    if (blockIdx.x == 0 && threadIdx.x == 0) {
        int run = 0;
        for (int b = 0; b < nb; ++b) { run += blksum[b]; blksum[b] = run; }
    }
}

__global__ void scan_add(int* rowptr, const int* __restrict__ blksum, int n) {
    int g = blockIdx.x * blockDim.x + threadIdx.x;
    if (g == 0) rowptr[0] = 0;
    if (g < n) {
        int b = g >> 10;
        if (b > 0) rowptr[g + 1] += blksum[b - 1];
    }
}

// ------- phase B: one block per bucket, scatter src into 12.5KB slice ---
__global__ void fillB(const int2* __restrict__ stage, const int* __restrict__ bcur,
                      const int* __restrict__ rowptr, int* __restrict__ csrs, int n) {
    __shared__ int lcur[256];
    int p = blockIdx.x;
    int lo = bucket_lo(p, n), hi = bucket_lo(p + 1, n);
    int nloc = hi - lo;
    for (int k = threadIdx.x; k < nloc; k += blockDim.x) lcur[k] = 0;
    __syncthreads();
    int s0 = p * BCAP, s1 = bcur[p];
    for (int i = s0 + threadIdx.x; i < s1; i += blockDim.x) {
        int2 ed = stage[i];
        int pos = rowptr[ed.y] + atomicAdd(&lcur[ed.y - lo], 1);
        csrs[pos] = ed.x;
    }
}

// ---------------- layer-1 aggregate on raw x (5-dim), thread = node ------
__global__ void gather5(const int* __restrict__ rowptr,
                        const int* __restrict__ csrs,
                        const float* __restrict__ dinv,
                        const float* __restrict__ x,
                        float* __restrict__ z, int n) {
    int i = blockIdx.x * blockDim.x + threadIdx.x;
    if (i >= n) return;
    float di = dinv[i];
    float ws = di * di;
    const float* xr = x + (size_t)i * 5;
    float4 x4 = *(const float4*)(xr);
    float a0 = x4.x * ws, a1 = x4.y * ws, a2 = x4.z * ws,
          a3 = x4.w * ws, a4 = xr[4] * ws;
    int end = rowptr[i + 1];
    for (int j = rowptr[i]; j < end; ++j) {
        int s = csrs[j];
        float w = dinv[s] * di;
        const float* r = x + (size_t)s * 5;
        float4 r4 = *(const float4*)(r);
        float r1 = r[4];
        a0 = fmaf(w, r4.x, a0);
        a1 = fmaf(w, r4.y, a1);
        a2 = fmaf(w, r4.z, a2);
        a3 = fmaf(w, r4.w, a3);
        a4 = fmaf(w, r1, a4);
    }
    float* zr = z + (size_t)i * 5;
    zr[0] = a0; zr[1] = a1; zr[2] = a2; zr[3] = a3; zr[4] = a4;
}

// ------- dense transform, 8 outputs x NODES nodes per thread -------------
template<int K, int DOUT, bool BR, int NODES>
__global__ void transformB(const float* __restrict__ xin,
                           const float* __restrict__ W,
                           const float* __restrict__ b,
                           float* __restrict__ out, int n) {
    const int C = DOUT / 8;
    int tid = blockIdx.x * blockDim.x + threadIdx.x;
    int grp = tid / C;
    int c = tid % C;
    int i0 = grp * NODES;
    if (i0 >= n) return;
    float acc[NODES][8];
#pragma unroll
    for (int nn = 0; nn < NODES; ++nn)
#pragma unroll
        for (int q = 0; q < 8; ++q) acc[nn][q] = 0.0f;

    static_assert(K % 4 == 0, "K multiple of 4");
    for (int k0 = 0; k0 < K; k0 += 4) {
        float4 r[NODES];
#pragma unroll
        for (int nn = 0; nn < NODES; ++nn) {
            int idx = i0 + nn < n ? i0 + nn : n - 1;
            r[nn] = *(const float4*)(xin + (size_t)idx * K + k0);
        }
#pragma unroll
        for (int kk = 0; kk < 4; ++kk) {
            const float* wp = W + (size_t)(k0 + kk) * DOUT + c * 8;
            float4 w0 = *(const float4*)(wp);
            float4 w1 = *(const float4*)(wp + 4);
#pragma unroll
            for (int nn = 0; nn < NODES; ++nn) {
                float v = (&r[nn].x)[kk];
                acc[nn][0] = fmaf(v, w0.x, acc[nn][0]);
                acc[nn][1] = fmaf(v, w0.y, acc[nn][1]);
                acc[nn][2] = fmaf(v, w0.z, acc[nn][2]);
                acc[nn][3] = fmaf(v, w0.w, acc[nn][3]);
                acc[nn][4] = fmaf(v, w1.x, acc[nn][4]);
                acc[nn][5] = fmaf(v, w1.y, acc[nn][5]);
                acc[nn][6] = fmaf(v, w1.z, acc[nn][6]);
                acc[nn][7] = fmaf(v, w1.w, acc[nn][7]);
            }
        }
    }
    float4 b0, b1;
    if (BR) {
        b0 = *(const float4*)(b + c * 8);
        b1 = *(const float4*)(b + c * 8 + 4);
    }
#pragma unroll
    for (int nn = 0; nn < NODES; ++nn) {
        if (i0 + nn >= n) break;
        float4 o0, o1;
        o0.x = acc[nn][0]; o0.y = acc[nn][1]; o0.z = acc[nn][2]; o0.w = acc[nn][3];
        o1.x = acc[nn][4]; o1.y = acc[nn][5]; o1.z = acc[nn][6]; o1.w = acc[nn][7];
        if (BR) {
            o0.x = fmaxf(o0.x + b0.x, 0.f); o0.y = fmaxf(o0.y + b0.y, 0.f);
            o0.z = fmaxf(o0.z + b0.z, 0.f); o0.w = fmaxf(o0.w + b0.w, 0.f);
            o1.x = fmaxf(o1.x + b1.x, 0.f); o1.y = fmaxf(o1.y + b1.y, 0.f);
            o1.z = fmaxf(o1.z + b1.z, 0.f); o1.w = fmaxf(o1.w + b1.w, 0.f);
        }
        float* op = out + (size_t)(i0 + nn) * DOUT + c * 8;
        *(float4*)(op) = o0;
        *(float4*)(op + 4) = o1;
    }
}

// ---- K=5 variant (layer 1) ---------------------------------------------
template<int DOUT, bool BR, int NODES>
__global__ void transformB5(const float* __restrict__ xin,
                            const float* __restrict__ W,
                            const float* __restrict__ b,
                            float* __restrict__ out, int n) {
    const int C = DOUT / 8;
    int tid = blockIdx.x * blockDim.x + threadIdx.x;
    int grp = tid / C;
    int c = tid % C;
    int i0 = grp * NODES;
    if (i0 >= n) return;
    float r[NODES][5];
#pragma unroll
    for (int nn = 0; nn < NODES; ++nn) {
        int idx = i0 + nn < n ? i0 + nn : n - 1;
        const float* row = xin + (size_t)idx * 5;
#pragma unroll
        for (int k = 0; k < 5; ++k) r[nn][k] = row[k];
    }
    float acc[NODES][8];
#pragma unroll
    for (int nn = 0; nn < NODES; ++nn)
#pragma unroll
        for (int q = 0; q < 8; ++q) acc[nn][q] = 0.0f;
#pragma unroll
    for (int k = 0; k < 5; ++k) {
        const float* wp = W + (size_t)k * DOUT + c * 8;
        float4 w0 = *(const float4*)(wp);
        float4 w1 = *(const float4*)(wp + 4);
#pragma unroll
        for (int nn = 0; nn < NODES; ++nn) {
            float v = r[nn][k];
            acc[nn][0] = fmaf(v, w0.x, acc[nn][0]);
            acc[nn][1] = fmaf(v, w0.y, acc[nn][1]);
            acc[nn][2] = fmaf(v, w0.z, acc[nn][2]);
            acc[nn][3] = fmaf(v, w0.w, acc[nn][3]);
            acc[nn][4] = fmaf(v, w1.x, acc[nn][4]);
            acc[nn][5] = fmaf(v, w1.y, acc[nn][5]);
            acc[nn][6] = fmaf(v, w1.z, acc[nn][6]);
            acc[nn][7] = fmaf(v, w1.w, acc[nn][7]);
        }
    }
    float4 b0, b1;
    if (BR) {
        b0 = *(const float4*)(b + c * 8);
        b1 = *(const float4*)(b + c * 8 + 4);
    }
#pragma unroll
    for (int nn = 0; nn < NODES; ++nn) {
        if (i0 + nn >= n) break;
        float4 o0, o1;
        o0.x = acc[nn][0]; o0.y = acc[nn][1]; o0.z = acc[nn][2]; o0.w = acc[nn][3];
        o1.x = acc[nn][4]; o1.y = acc[nn][5]; o1.z = acc[nn][6]; o1.w = acc[nn][7];
        if (BR) {
            o0.x = fmaxf(o0.x + b0.x, 0.f); o0.y = fmaxf(o0.y + b0.y, 0.f);
            o0.z = fmaxf(o0.z + b0.z, 0.f); o0.w = fmaxf(o0.w + b0.w, 0.f);
            o1.x = fmaxf(o1.x + b1.x, 0.f); o1.y = fmaxf(o1.y + b1.y, 0.f);
            o1.z = fmaxf(o1.z + b1.z, 0.f); o1.w = fmaxf(o1.w + b1.w, 0.f);
        }
        float* op = out + (size_t)(i0 + nn) * DOUT + c * 8;
        *(float4*)(op) = o0;
        *(float4*)(op + 4) = o1;
    }
}

// ------- per-node gather (64-dim): 16 lanes/node, float4 per lane --------
template<bool BR>
__global__ void gather4(const int* __restrict__ rowptr,
                        const int* __restrict__ csrs,
                        const float* __restrict__ dinv,
                        const float* __restrict__ b,
                        const float* __restrict__ t,   // [n][64]
                        float* __restrict__ h, int n) {
    int tid = blockIdx.x * blockDim.x + threadIdx.x;
    int i = tid >> 4;
    int c = tid & 15;
    if (i >= n) return;
    float di = dinv[i];
    float ws = di * di;
    float4 sv = *(const float4*)(t + (size_t)i * 64 + c * 4);
    float4 a0, a1 = {0.f, 0.f, 0.f, 0.f};
    a0.x = sv.x * ws; a0.y = sv.y * ws; a0.z = sv.z * ws; a0.w = sv.w * ws;
    if (BR) {
        float4 bb = *(const float4*)(b + c * 4);
        a0.x += bb.x; a0.y += bb.y; a0.z += bb.z; a0.w += bb.w;
    }
    int j = rowptr[i], end = rowptr[i + 1];
    for (; j + 1 < end; j += 2) {
        int s0 = csrs[j], s1 = csrs[j + 1];
        float w0 = dinv[s0] * di, w1 = dinv[s1] * di;
        float4 v0 = *(const float4*)(t + (size_t)s0 * 64 + c * 4);
        float4 v1 = *(const float4*)(t + (size_t)s1 * 64 + c * 4);
        a0.x = fmaf(w0, v0.x, a0.x); a0.y = fmaf(w0, v0.y, a0.y);
        a0.z = fmaf(w0, v0.z, a0.z); a0.w = fmaf(w0, v0.w, a0.w);
        a1.x = fmaf(w1, v1.x, a1.x); a1.y = fmaf(w1, v1.y, a1.y);
        a1.z = fmaf(w1, v1.z, a1.z); a1.w = fmaf(w1, v1.w, a1.w);
    }
    if (j < end) {
        int s0 = csrs[j];
        float w0 = dinv[s0] * di;
        float4 v0 = *(const float4*)(t + (size_t)s0 * 64 + c * 4);
        a0.x = fmaf(w0, v0.x, a0.x); a0.y = fmaf(w0, v0.y, a0.y);
        a0.z = fmaf(w0, v0.z, a0.z); a0.w = fmaf(w0, v0.w, a0.w);
    }
    float4 o;
    o.x = a0.x + a1.x; o.y = a0.y + a1.y; o.z = a0.z + a1.z; o.w = a0.w + a1.w;
    if (BR) {
        o.x = fmaxf(o.x, 0.f); o.y = fmaxf(o.y, 0.f);
        o.z = fmaxf(o.z, 0.f); o.w = fmaxf(o.w, 0.f);
    }
    *(float4*)(h + (size_t)i * 64 + c * 4) = o;
}

// ------- pooling + FC + sigmoid: 4 waves per graph, LDS combine ---------
__global__ void pool(const float* __restrict__ h3, const int* __restrict__ batch,
                     const float* __restrict__ Wfc, const float* __restrict__ bfc,
                     float* __restrict__ out, int n) {
    int g = blockIdx.x;
    int lane = threadIdx.x & 63;
    int w = threadIdx.x >> 6;  // 0..3
    int lo = 0, hi = n;
    while (lo < hi) { int m = (lo + hi) >> 1; if (batch[m] < g) lo = m + 1; else hi = m; }
    int start = lo;
    hi = n;
    while (lo < hi) { int m = (lo + hi) >> 1; if (batch[m] < g + 1) lo = m + 1; else hi = m; }
    int end = lo;
    float a0 = 0.f, a1 = 0.f, a2 = 0.f, a3 = 0.f;
    int m = start + w;
    for (; m + 12 < end; m += 16) {
        a0 += h3[(size_t)m * 64 + lane];
        a1 += h3[(size_t)(m + 4) * 64 + lane];
        a2 += h3[(size_t)(m + 8) * 64 + lane];
        a3 += h3[(size_t)(m + 12) * 64 + lane];
    }
    for (; m < end; m += 4) a0 += h3[(size_t)m * 64 + lane];
    __shared__ float sh[4][64];
    sh[w][lane] = (a0 + a1) + (a2 + a3);
    __syncthreads();
    if (w == 0) {
        float v = (sh[0][lane] + sh[1][lane]) + (sh[2][lane] + sh[3][lane]);
        float cnt = (float)(end - start);
        v = (v / fmaxf(cnt, 1.0f)) * Wfc[lane];
#pragma unroll
        for (int off = 32; off > 0; off >>= 1) v += __shfl_down(v, off, 64);
        if (lane == 0) out[g] = 1.0f / (1.0f + expf(-(v + bfc[0])));
    }
}

static inline int cdiv(long long a, int b) { return (int)((a + b - 1) / b); }

extern "C" void kernel_launch(void* const* d_in, const int* in_sizes, int n_in,
                              void* d_out, int out_size, void* d_ws, size_t ws_size,
                              hipStream_t stream) {
    const float* x   = (const float*)d_in[0];
    const int*   ei  = (const int*)d_in[1];
    const int*   bat = (const int*)d_in[2];
    const float* W1  = (const float*)d_in[3];
    const float* b1  = (const float*)d_in[4];
    const float* W2  = (const float*)d_in[5];
    const float* b2  = (const float*)d_in[6];
    const float* W3  = (const float*)d_in[7];
    const float* b3  = (const float*)d_in[8];
    const float* Wfc = (const float*)d_in[9];
    const float* bfc = (const float*)d_in[10];
    float* out = (float*)d_out;

    const int N = in_sizes[0] / 5;   // 100000
    const int E = in_sizes[1] / 2;   // 1600000
    const int* src = ei;
    const int* dst = ei + E;

    // ---- workspace layout ----
    float* ws    = (float*)d_ws;
    float* dinv  = ws;                          // N
    int*   deg   = (int*)(dinv + N);            // N
    int*   rowptr= deg + N;                     // N+4
    int*   blksum= rowptr + N + 4;              // 128
    int*   bcur  = blksum + 128;                // NBK
    int*   csrs  = bcur + NBK;                  // E (src only, 4B/edge)
    float* A     = (float*)(csrs + E);          // N*128
    float* B     = A + (size_t)N * 128;         // N*128
    int2*  stage = (int2*)A;                    // NBK*BCAP*8B = 14.7MB, aliases A
                                                // (consumed before gather5 writes A)

    const int Blk = 256;
    const int NB = cdiv(N, 1024);

    // ---- CSR build: bucket sort -> per-bucket hist -> scan -> fill ----
    zero_bcur<<<2, 256, 0, stream>>>(bcur);
    bucketA<<<256, 256, 0, stream>>>(src, dst, bcur, stage, E, N);
    histB<<<NBK, 256, 0, stream>>>(stage, bcur, deg, N);
    make_dinv<<<cdiv(N, Blk), Blk, 0, stream>>>(deg, dinv, N);
    scan_blk<<<NB, 1024, 0, stream>>>(deg, rowptr, blksum, N);
    scan_sums<<<1, 64, 0, stream>>>(blksum, NB);
    scan_add<<<cdiv(N, Blk), Blk, 0, stream>>>(rowptr, blksum, N);
    fillB<<<NBK, 256, 0, stream>>>(stage, bcur, rowptr, csrs, N);

    // ---- layer 1: aggregate raw x (5-dim), then 5->64 + relu ----
    gather5<<<cdiv(N, Blk), Blk, 0, stream>>>(rowptr, csrs, dinv, x, A, N);
    transformB5<64, true, 4><<<cdiv((long long)cdiv(N, 4) * 8, Blk), Blk, 0, stream>>>(
        A, W1, b1, B, N);                                   // h1 -> B

    // ---- layer 2: aggregate h1 (64-dim), then 64->128 + relu ----
    gather4<false><<<cdiv((long long)N * 16, Blk), Blk, 0, stream>>>(
        rowptr, csrs, dinv, nullptr, B, A, N);              // z2 -> A
    transformB<64, 128, true, 8><<<cdiv((long long)cdiv(N, 8) * 16, Blk), Blk, 0, stream>>>(
        A, W2, b2, B, N);                                   // h2 -> B

    // ---- layer 3: 128->64 first, then aggregate + bias + relu ----
    transformB<128, 64, false, 8><<<cdiv((long long)cdiv(N, 8) * 8, Blk), Blk, 0, stream>>>(
        B, W3, nullptr, A, N);                              // t3 -> A
    gather4<true><<<cdiv((long long)N * 16, Blk), Blk, 0, stream>>>(
        rowptr, csrs, dinv, b3, A, B, N);                   // h3 -> B

    // ---- pooling + FC head ----
    pool<<<NG, 256, 0, stream>>>(B, bat, Wfc, bfc, out, N);
}

// Round 7
// 474.190 us; speedup vs baseline: 1.2797x; 1.1099x over previous
//
#include <hip/hip_runtime.h>
#include <math.h>

#define NG 256
#define NBK 512          // sort buckets
#define BCAP 3584        // per-bucket staging capacity (mean 3125, +8 sigma)

static __device__ __forceinline__ int bucket_lo(int p, int n) {
    return (int)(((long long)p * n + NBK - 1) / NBK);   // ceil(p*n/NBK)
}

// ---- bf16 helpers (tables stored as packed pairs in uint) ----
static __device__ __forceinline__ float blo(unsigned u) {
    return __uint_as_float(u << 16);
}
static __device__ __forceinline__ float bhi(unsigned u) {
    return __uint_as_float(u & 0xFFFF0000u);
}
static __device__ __forceinline__ unsigned packbf(float a, float b) {
    unsigned ua = __float_as_uint(a);
    ua = (ua + 0x7FFFu + ((ua >> 16) & 1u)) >> 16;          // RNE, low half
    unsigned ub = __float_as_uint(b);
    ub = (ub + 0x7FFFu + ((ub >> 16) & 1u)) & 0xFFFF0000u;  // RNE, high half
    return ua | ub;
}

// ---------------- bucket cursor init ----------------
__global__ void zero_bcur(int* bcur) {
    int i = blockIdx.x * blockDim.x + threadIdx.x;
    if (i < NBK) bcur[i] = i * BCAP;
}

// ------- phase A: bucket edges by dst; staged record = (src<<8)|local_dst --
__global__ void bucketA(const int* __restrict__ src, const int* __restrict__ dst,
                        int* bcur, unsigned* stage, int e, int n) {
    __shared__ int cnt[NBK];
    __shared__ int base[NBK];
    int nb = gridDim.x;
    int c0 = (int)((long long)blockIdx.x * e / nb);
    int c1 = (int)((long long)(blockIdx.x + 1) * e / nb);
    for (int k = threadIdx.x; k < NBK; k += blockDim.x) cnt[k] = 0;
    __syncthreads();
    for (int i = c0 + threadIdx.x; i < c1; i += blockDim.x) {
        int d = dst[i];
        int p = (int)((long long)d * NBK / n);
        atomicAdd(&cnt[p], 1);
    }
    __syncthreads();
    for (int k = threadIdx.x; k < NBK; k += blockDim.x)
        base[k] = atomicAdd(&bcur[k], cnt[k]);
    __syncthreads();
    for (int k = threadIdx.x; k < NBK; k += blockDim.x) cnt[k] = 0;
    __syncthreads();
    for (int i = c0 + threadIdx.x; i < c1; i += blockDim.x) {
        int s = src[i], d = dst[i];
        int p = (int)((long long)d * NBK / n);
        int ldst = d - bucket_lo(p, n);           // < 196, fits 8 bits
        int lp = atomicAdd(&cnt[p], 1);
        stage[base[p] + lp] = ((unsigned)s << 8) | (unsigned)ldst;
    }
}

// ------- per-bucket degree histogram (LDS counters, coalesced write) ----
__global__ void histB(const unsigned* __restrict__ stage, const int* __restrict__ bcur,
                      int* __restrict__ deg, int n) {
    __shared__ int ldeg[256];
    int p = blockIdx.x;
    int lo = bucket_lo(p, n), hi = bucket_lo(p + 1, n);
    int nloc = hi - lo;
    for (int k = threadIdx.x; k < nloc; k += blockDim.x) ldeg[k] = 0;
    __syncthreads();
    int s0 = p * BCAP, s1 = bcur[p];
    for (int i = s0 + threadIdx.x; i < s1; i += blockDim.x)
        atomicAdd(&ldeg[stage[i] & 255u], 1);
    __syncthreads();
    for (int k = threadIdx.x; k < nloc; k += blockDim.x) deg[lo + k] = ldeg[k];
}

__global__ void make_dinv(const int* __restrict__ deg, float* dinv, int n) {
    int i = blockIdx.x * blockDim.x + threadIdx.x;
    if (i < n) dinv[i] = rsqrtf((float)deg[i] + 1.0f);  // +1 self-loop
}

// ---------------- exclusive scan of deg -> rowptr ----------------
__global__ void scan_blk(const int* __restrict__ deg, int* rowptr,
                         int* blksum, int n) {
    __shared__ int sh[1024];
    int tid = threadIdx.x;
    int g = blockIdx.x * 1024 + tid;
    int v = (g < n) ? deg[g] : 0;
    sh[tid] = v;
    __syncthreads();
    for (int off = 1; off < 1024; off <<= 1) {
        int t = (tid >= off) ? sh[tid - off] : 0;
        __syncthreads();
        sh[tid] += t;
        __syncthreads();
    }
    if (g < n) rowptr[g + 1] = sh[tid];
    if (tid == 1023) blksum[blockIdx.x] = sh[1023];
}

__global__ void scan_sums(int* blksum, int nb) {
    if (blockIdx.x == 0 && threadIdx.x == 0) {
        int run = 0;
        for (int b = 0; b < nb; ++b) { run += blksum[b]; blksum[b] = run; }
    }
}

__global__ void scan_add(int* rowptr, const int* __restrict__ blksum, int n) {
    int g = blockIdx.x * blockDim.x + threadIdx.x;
    if (g == 0) rowptr[0] = 0;
    if (g < n) {
        int b = g >> 10;
        if (b > 0) rowptr[g + 1] += blksum[b - 1];
    }
}

// ------- phase B: one block per bucket, scatter src into 12.5KB slice ---
__global__ void fillB(const unsigned* __restrict__ stage, const int* __restrict__ bcur,
                      const int* __restrict__ rowptr, int* __restrict__ csrs, int n) {
    __shared__ int lcur[256];
    int p = blockIdx.x;
    int lo = bucket_lo(p, n), hi = bucket_lo(p + 1, n);
    int nloc = hi - lo;
    for (int k = threadIdx.x; k < nloc; k += blockDim.x) lcur[k] = 0;
    __syncthreads();
    int s0 = p * BCAP, s1 = bcur[p];
    for (int i = s0 + threadIdx.x; i < s1; i += blockDim.x) {
        unsigned pk = stage[i];
        int ldst = (int)(pk & 255u);
        int pos = rowptr[lo + ldst] + atomicAdd(&lcur[ldst], 1);
        csrs[pos] = (int)(pk >> 8);
    }
}

// ---------------- layer-1 aggregate on raw x (5-dim), thread = node ------
__global__ void gather5(const int* __restrict__ rowptr,
                        const int* __restrict__ csrs,
                        const float* __restrict__ dinv,
                        const float* __restrict__ x,
                        float* __restrict__ z, int n) {
    int i = blockIdx.x * blockDim.x + threadIdx.x;
    if (i >= n) return;
    float di = dinv[i];
    float ws = di * di;
    const float* xr = x + (size_t)i * 5;
    float4 x4 = *(const float4*)(xr);
    float a0 = x4.x * ws, a1 = x4.y * ws, a2 = x4.z * ws,
          a3 = x4.w * ws, a4 = xr[4] * ws;
    int end = rowptr[i + 1];
    for (int j = rowptr[i]; j < end; ++j) {
        int s = csrs[j];
        float w = dinv[s] * di;
        const float* r = x + (size_t)s * 5;
        float4 r4 = *(const float4*)(r);
        float r1 = r[4];
        a0 = fmaf(w, r4.x, a0);
        a1 = fmaf(w, r4.y, a1);
        a2 = fmaf(w, r4.z, a2);
        a3 = fmaf(w, r4.w, a3);
        a4 = fmaf(w, r1, a4);
    }
    float* zr = z + (size_t)i * 5;
    zr[0] = a0; zr[1] = a1; zr[2] = a2; zr[3] = a3; zr[4] = a4;
}

// ---- transform epilogue shared by both kernels --------------------------
template<int DOUT, bool BR, bool SCALE, bool OUTBF>
static __device__ __forceinline__ void emit(float o[8], const float* b, int c,
                                            float dsc, void* out, int i) {
    if (BR) {
        float4 b0 = *(const float4*)(b + c * 8);
        float4 b1 = *(const float4*)(b + c * 8 + 4);
        o[0] = fmaxf(o[0] + b0.x, 0.f); o[1] = fmaxf(o[1] + b0.y, 0.f);
        o[2] = fmaxf(o[2] + b0.z, 0.f); o[3] = fmaxf(o[3] + b0.w, 0.f);
        o[4] = fmaxf(o[4] + b1.x, 0.f); o[5] = fmaxf(o[5] + b1.y, 0.f);
        o[6] = fmaxf(o[6] + b1.z, 0.f); o[7] = fmaxf(o[7] + b1.w, 0.f);
    }
    if (SCALE) {
#pragma unroll
        for (int q = 0; q < 8; ++q) o[q] *= dsc;
    }
    if (OUTBF) {
        uint4 pk;
        pk.x = packbf(o[0], o[1]); pk.y = packbf(o[2], o[3]);
        pk.z = packbf(o[4], o[5]); pk.w = packbf(o[6], o[7]);
        *(uint4*)((unsigned*)out + (size_t)i * (DOUT / 2) + c * 4) = pk;
    } else {
        float* op = (float*)out + (size_t)i * DOUT + c * 8;
        float4 o0 = {o[0], o[1], o[2], o[3]};
        float4 o1 = {o[4], o[5], o[6], o[7]};
        *(float4*)(op) = o0;
        *(float4*)(op + 4) = o1;
    }
}

// ------- dense transform, 8 outputs x NODES nodes per thread -------------
template<int K, int DOUT, bool BR, bool SCALE, bool OUTBF, int NODES>
__global__ void transformB(const float* __restrict__ xin,
                           const float* __restrict__ W,
                           const float* __restrict__ b,
                           const float* __restrict__ dinv,
                           void* __restrict__ out, int n) {
    const int C = DOUT / 8;
    int tid = blockIdx.x * blockDim.x + threadIdx.x;
    int grp = tid / C;
    int c = tid % C;
    int i0 = grp * NODES;
    if (i0 >= n) return;
    float acc[NODES][8];
#pragma unroll
    for (int nn = 0; nn < NODES; ++nn)
#pragma unroll
        for (int q = 0; q < 8; ++q) acc[nn][q] = 0.0f;

    static_assert(K % 4 == 0, "K multiple of 4");
    for (int k0 = 0; k0 < K; k0 += 4) {
        float4 r[NODES];
#pragma unroll
        for (int nn = 0; nn < NODES; ++nn) {
            int idx = i0 + nn < n ? i0 + nn : n - 1;
            r[nn] = *(const float4*)(xin + (size_t)idx * K + k0);
        }
#pragma unroll
        for (int kk = 0; kk < 4; ++kk) {
            const float* wp = W + (size_t)(k0 + kk) * DOUT + c * 8;
            float4 w0 = *(const float4*)(wp);
            float4 w1 = *(const float4*)(wp + 4);
#pragma unroll
            for (int nn = 0; nn < NODES; ++nn) {
                float v = (&r[nn].x)[kk];
                acc[nn][0] = fmaf(v, w0.x, acc[nn][0]);
                acc[nn][1] = fmaf(v, w0.y, acc[nn][1]);
                acc[nn][2] = fmaf(v, w0.z, acc[nn][2]);
                acc[nn][3] = fmaf(v, w0.w, acc[nn][3]);
                acc[nn][4] = fmaf(v, w1.x, acc[nn][4]);
                acc[nn][5] = fmaf(v, w1.y, acc[nn][5]);
                acc[nn][6] = fmaf(v, w1.z, acc[nn][6]);
                acc[nn][7] = fmaf(v, w1.w, acc[nn][7]);
            }
        }
    }
#pragma unroll
    for (int nn = 0; nn < NODES; ++nn) {
        if (i0 + nn >= n) break;
        float dsc = SCALE ? dinv[i0 + nn] : 1.0f;
        emit<DOUT, BR, SCALE, OUTBF>(acc[nn], b, c, dsc, out, i0 + nn);
    }
}

// ---- K=5 variant (layer 1) ---------------------------------------------
template<int DOUT, bool BR, bool SCALE, bool OUTBF, int NODES>
__global__ void transformB5(const float* __restrict__ xin,
                            const float* __restrict__ W,
                            const float* __restrict__ b,
                            const float* __restrict__ dinv,
                            void* __restrict__ out, int n) {
    const int C = DOUT / 8;
    int tid = blockIdx.x * blockDim.x + threadIdx.x;
    int grp = tid / C;
    int c = tid % C;
    int i0 = grp * NODES;
    if (i0 >= n) return;
    float r[NODES][5];
#pragma unroll
    for (int nn = 0; nn < NODES; ++nn) {
        int idx = i0 + nn < n ? i0 + nn : n - 1;
        const float* row = xin + (size_t)idx * 5;
#pragma unroll
        for (int k = 0; k < 5; ++k) r[nn][k] = row[k];
    }
    float acc[NODES][8];
#pragma unroll
    for (int nn = 0; nn < NODES; ++nn)
#pragma unroll
        for (int q = 0; q < 8; ++q) acc[nn][q] = 0.0f;
#pragma unroll
    for (int k = 0; k < 5; ++k) {
        const float* wp = W + (size_t)k * DOUT + c * 8;
        float4 w0 = *(const float4*)(wp);
        float4 w1 = *(const float4*)(wp + 4);
#pragma unroll
        for (int nn = 0; nn < NODES; ++nn) {
            float v = r[nn][k];
            acc[nn][0] = fmaf(v, w0.x, acc[nn][0]);
            acc[nn][1] = fmaf(v, w0.y, acc[nn][1]);
            acc[nn][2] = fmaf(v, w0.z, acc[nn][2]);
            acc[nn][3] = fmaf(v, w0.w, acc[nn][3]);
            acc[nn][4] = fmaf(v, w1.x, acc[nn][4]);
            acc[nn][5] = fmaf(v, w1.y, acc[nn][5]);
            acc[nn][6] = fmaf(v, w1.z, acc[nn][6]);
            acc[nn][7] = fmaf(v, w1.w, acc[nn][7]);
        }
    }
#pragma unroll
    for (int nn = 0; nn < NODES; ++nn) {
        if (i0 + nn >= n) break;
        float dsc = SCALE ? dinv[i0 + nn] : 1.0f;
        emit<DOUT, BR, SCALE, OUTBF>(acc[nn], b, c, dsc, out, i0 + nn);
    }
}

// ------- 64-dim gather from bf16 table (dinv pre-folded into table) ------
// z[i] = dinv[i] * (g[i] + sum_src g[s]);   8 lanes/node, 8 feats/lane
template<bool BR>
__global__ void gatherBF(const int* __restrict__ rowptr,
                         const int* __restrict__ csrs,
                         const float* __restrict__ dinv,
                         const float* __restrict__ b,
                         const unsigned* __restrict__ g,   // [n][32] packed bf16
                         float* __restrict__ z, int n) {
    int tid = blockIdx.x * blockDim.x + threadIdx.x;
    int i = tid >> 3;
    int c = tid & 7;
    if (i >= n) return;
    uint4 sv = *(const uint4*)(g + (size_t)i * 32 + c * 4);
    float a0[8], a1[8];
    a0[0] = blo(sv.x); a0[1] = bhi(sv.x); a0[2] = blo(sv.y); a0[3] = bhi(sv.y);
    a0[4] = blo(sv.z); a0[5] = bhi(sv.z); a0[6] = blo(sv.w); a0[7] = bhi(sv.w);
#pragma unroll
    for (int q = 0; q < 8; ++q) a1[q] = 0.0f;
    int j = rowptr[i], end = rowptr[i + 1];
    for (; j + 1 < end; j += 2) {
        int s0 = csrs[j], s1 = csrs[j + 1];
        uint4 v0 = *(const uint4*)(g + (size_t)s0 * 32 + c * 4);
        uint4 v1 = *(const uint4*)(g + (size_t)s1 * 32 + c * 4);
        a0[0] += blo(v0.x); a0[1] += bhi(v0.x); a0[2] += blo(v0.y); a0[3] += bhi(v0.y);
        a0[4] += blo(v0.z); a0[5] += bhi(v0.z); a0[6] += blo(v0.w); a0[7] += bhi(v0.w);
        a1[0] += blo(v1.x); a1[1] += bhi(v1.x); a1[2] += blo(v1.y); a1[3] += bhi(v1.y);
        a1[4] += blo(v1.z); a1[5] += bhi(v1.z); a1[6] += blo(v1.w); a1[7] += bhi(v1.w);
    }
    if (j < end) {
        int s0 = csrs[j];
        uint4 v0 = *(const uint4*)(g + (size_t)s0 * 32 + c * 4);
        a0[0] += blo(v0.x); a0[1] += bhi(v0.x); a0[2] += blo(v0.y); a0[3] += bhi(v0.y);
        a0[4] += blo(v0.z); a0[5] += bhi(v0.z); a0[6] += blo(v0.w); a0[7] += bhi(v0.w);
    }
    float di = dinv[i];
    float o[8];
#pragma unroll
    for (int q = 0; q < 8; ++q) o[q] = di * (a0[q] + a1[q]);
    if (BR) {
        float4 b0 = *(const float4*)(b + c * 8);
        float4 b1 = *(const float4*)(b + c * 8 + 4);
        o[0] = fmaxf(o[0] + b0.x, 0.f); o[1] = fmaxf(o[1] + b0.y, 0.f);
        o[2] = fmaxf(o[2] + b0.z, 0.f); o[3] = fmaxf(o[3] + b0.w, 0.f);
        o[4] = fmaxf(o[4] + b1.x, 0.f); o[5] = fmaxf(o[5] + b1.y, 0.f);
        o[6] = fmaxf(o[6] + b1.z, 0.f); o[7] = fmaxf(o[7] + b1.w, 0.f);
    }
    float* zp = z + (size_t)i * 64 + c * 8;
    float4 z0 = {o[0], o[1], o[2], o[3]};
    float4 z1 = {o[4], o[5], o[6], o[7]};
    *(float4*)(zp) = z0;
    *(float4*)(zp + 4) = z1;
}

// ------- pooling + FC + sigmoid: 4 waves per graph, LDS combine ---------
__global__ void pool(const float* __restrict__ h3, const int* __restrict__ batch,
                     const float* __restrict__ Wfc, const float* __restrict__ bfc,
                     float* __restrict__ out, int n) {
    int g = blockIdx.x;
    int lane = threadIdx.x & 63;
    int w = threadIdx.x >> 6;  // 0..3
    int lo = 0, hi = n;
    while (lo < hi) { int m = (lo + hi) >> 1; if (batch[m] < g) lo = m + 1; else hi = m; }
    int start = lo;
    hi = n;
    while (lo < hi) { int m = (lo + hi) >> 1; if (batch[m] < g + 1) lo = m + 1; else hi = m; }
    int end = lo;
    float a0 = 0.f, a1 = 0.f, a2 = 0.f, a3 = 0.f;
    int m = start + w;
    for (; m + 12 < end; m += 16) {
        a0 += h3[(size_t)m * 64 + lane];
        a1 += h3[(size_t)(m + 4) * 64 + lane];
        a2 += h3[(size_t)(m + 8) * 64 + lane];
        a3 += h3[(size_t)(m + 12) * 64 + lane];
    }
    for (; m < end; m += 4) a0 += h3[(size_t)m * 64 + lane];
    __shared__ float sh[4][64];
    sh[w][lane] = (a0 + a1) + (a2 + a3);
    __syncthreads();
    if (w == 0) {
        float v = (sh[0][lane] + sh[1][lane]) + (sh[2][lane] + sh[3][lane]);
        float cnt = (float)(end - start);
        v = (v / fmaxf(cnt, 1.0f)) * Wfc[lane];
#pragma unroll
        for (int off = 32; off > 0; off >>= 1) v += __shfl_down(v, off, 64);
        if (lane == 0) out[g] = 1.0f / (1.0f + expf(-(v + bfc[0])));
    }
}

static inline int cdiv(long long a, int b) { return (int)((a + b - 1) / b); }

extern "C" void kernel_launch(void* const* d_in, const int* in_sizes, int n_in,
                              void* d_out, int out_size, void* d_ws, size_t ws_size,
                              hipStream_t stream) {
    const float* x   = (const float*)d_in[0];
    const int*   ei  = (const int*)d_in[1];
    const int*   bat = (const int*)d_in[2];
    const float* W1  = (const float*)d_in[3];
    const float* b1  = (const float*)d_in[4];
    const float* W2  = (const float*)d_in[5];
    const float* b2  = (const float*)d_in[6];
    const float* W3  = (const float*)d_in[7];
    const float* b3  = (const float*)d_in[8];
    const float* Wfc = (const float*)d_in[9];
    const float* bfc = (const float*)d_in[10];
    float* out = (float*)d_out;

    const int N = in_sizes[0] / 5;   // 100000
    const int E = in_sizes[1] / 2;   // 1600000
    const int* src = ei;
    const int* dst = ei + E;

    // ---- workspace layout ----
    float* ws     = (float*)d_ws;
    float* dinv   = ws;                          // N
    int*   deg    = (int*)(dinv + N);            // N
    int*   rowptr = deg + N;                     // N+4
    int*   blksum = rowptr + N + 4;              // 128
    int*   bcur   = blksum + 128;                // NBK
    int*   csrs   = bcur + NBK;                  // E (src only)
    float* A      = (float*)(csrs + E);          // N*128 floats
    float* B      = A + (size_t)N * 128;         // N*128 floats
    // aliases (sequential lifetimes):
    unsigned* stage = (unsigned*)A;              // NBK*BCAP uints (7.3MB), dead after fillB
    float*    z1    = A;                         // N*5
    unsigned* h1bf  = (unsigned*)B;              // N*32 (bf16 table, dinv-folded)
    float*    z2    = A;                         // N*64 (z1 dead)
    float*    h2    = B;                         // N*128 (h1bf dead)
    unsigned* t3bf  = (unsigned*)A;              // N*32 (z2 dead)
    float*    h3    = B;                         // N*64 (h2 dead)

    const int Blk = 256;
    const int NB = cdiv(N, 1024);

    // ---- CSR build: bucket sort -> per-bucket hist -> scan -> fill ----
    zero_bcur<<<2, 256, 0, stream>>>(bcur);
    bucketA<<<256, 256, 0, stream>>>(src, dst, bcur, stage, E, N);
    histB<<<NBK, 256, 0, stream>>>(stage, bcur, deg, N);
    make_dinv<<<cdiv(N, Blk), Blk, 0, stream>>>(deg, dinv, N);
    scan_blk<<<NB, 1024, 0, stream>>>(deg, rowptr, blksum, N);
    scan_sums<<<1, 64, 0, stream>>>(blksum, NB);
    scan_add<<<cdiv(N, Blk), Blk, 0, stream>>>(rowptr, blksum, N);
    fillB<<<NBK, 256, 0, stream>>>(stage, bcur, rowptr, csrs, N);

    // ---- layer 1: aggregate raw x (5-dim); 5->64 +bias+relu, ->bf16*dinv --
    gather5<<<cdiv(N, Blk), Blk, 0, stream>>>(rowptr, csrs, dinv, x, z1, N);
    transformB5<64, true, true, true, 4>
        <<<cdiv((long long)cdiv(N, 4) * 8, Blk), Blk, 0, stream>>>(
        z1, W1, b1, dinv, h1bf, N);

    // ---- layer 2: gather bf16 h1 -> z2; 64->128 +bias+relu (fp32) ----
    gatherBF<false><<<cdiv((long long)N * 8, Blk), Blk, 0, stream>>>(
        rowptr, csrs, dinv, nullptr, h1bf, z2, N);
    transformB<64, 128, true, false, false, 8>
        <<<cdiv((long long)cdiv(N, 8) * 16, Blk), Blk, 0, stream>>>(
        z2, W2, b2, nullptr, h2, N);

    // ---- layer 3: 128->64 (no bias), ->bf16*dinv; gather +bias+relu ----
    transformB<128, 64, false, true, true, 8>
        <<<cdiv((long long)cdiv(N, 8) * 8, Blk), Blk, 0, stream>>>(
        h2, W3, nullptr, dinv, t3bf, N);
    gatherBF<true><<<cdiv((long long)N * 8, Blk), Blk, 0, stream>>>(
        rowptr, csrs, dinv, b3, t3bf, h3, N);

    // ---- pooling + FC head ----
    pool<<<NG, 256, 0, stream>>>(h3, bat, Wfc, bfc, out, N);
}

// Round 9
// 449.721 us; speedup vs baseline: 1.3493x; 1.0544x over previous
//
#include <hip/hip_runtime.h>
#include <math.h>

#define NG 256
#define NBK 512          // sort buckets
#define BCAP 3584        // per-bucket staging capacity (mean 3125, +8 sigma)

static __device__ __forceinline__ int bucket_lo(int p, int n) {
    return (int)(((long long)p * n + NBK - 1) / NBK);   // ceil(p*n/NBK)
}

// ---- bf16 helpers (tables stored as packed pairs in uint) ----
static __device__ __forceinline__ float blo(unsigned u) {
    return __uint_as_float(u << 16);
}
static __device__ __forceinline__ float bhi(unsigned u) {
    return __uint_as_float(u & 0xFFFF0000u);
}
static __device__ __forceinline__ unsigned packbf(float a, float b) {
    unsigned ua = __float_as_uint(a);
    ua = (ua + 0x7FFFu + ((ua >> 16) & 1u)) >> 16;          // RNE, low half
    unsigned ub = __float_as_uint(b);
    ub = (ub + 0x7FFFu + ((ub >> 16) & 1u)) & 0xFFFF0000u;  // RNE, high half
    return ua | ub;
}

// ---------------- bucket cursor init ----------------
__global__ void zero_bcur(int* bcur) {
    int i = blockIdx.x * blockDim.x + threadIdx.x;
    if (i < NBK) bcur[i] = i * BCAP;
}

// ------- phase A: bucket edges by dst; staged record = (src<<8)|local_dst --
__global__ void bucketA(const int* __restrict__ src, const int* __restrict__ dst,
                        int* bcur, unsigned* stage, int e, int n) {
    __shared__ int cnt[NBK];
    __shared__ int base[NBK];
    int nb = gridDim.x;
    int c0 = (int)((long long)blockIdx.x * e / nb);
    int c1 = (int)((long long)(blockIdx.x + 1) * e / nb);
    for (int k = threadIdx.x; k < NBK; k += blockDim.x) cnt[k] = 0;
    __syncthreads();
    for (int i = c0 + threadIdx.x; i < c1; i += blockDim.x) {
        int d = dst[i];
        int p = (int)((long long)d * NBK / n);
        atomicAdd(&cnt[p], 1);
    }
    __syncthreads();
    for (int k = threadIdx.x; k < NBK; k += blockDim.x)
        base[k] = atomicAdd(&bcur[k], cnt[k]);
    __syncthreads();
    for (int k = threadIdx.x; k < NBK; k += blockDim.x) cnt[k] = 0;
    __syncthreads();
    for (int i = c0 + threadIdx.x; i < c1; i += blockDim.x) {
        int s = src[i], d = dst[i];
        int p = (int)((long long)d * NBK / n);
        int ldst = d - bucket_lo(p, n);           // < 196, fits 8 bits
        int lp = atomicAdd(&cnt[p], 1);
        stage[base[p] + lp] = ((unsigned)s << 8) | (unsigned)ldst;
    }
}

// ------- per-bucket degree histogram (LDS counters, coalesced write) ----
__global__ void histB(const unsigned* __restrict__ stage, const int* __restrict__ bcur,
                      int* __restrict__ deg, int n) {
    __shared__ int ldeg[256];
    int p = blockIdx.x;
    int lo = bucket_lo(p, n), hi = bucket_lo(p + 1, n);
    int nloc = hi - lo;
    for (int k = threadIdx.x; k < nloc; k += blockDim.x) ldeg[k] = 0;
    __syncthreads();
    int s0 = p * BCAP, s1 = bcur[p];
    for (int i = s0 + threadIdx.x; i < s1; i += blockDim.x)
        atomicAdd(&ldeg[stage[i] & 255u], 1);
    __syncthreads();
    for (int k = threadIdx.x; k < nloc; k += blockDim.x) deg[lo + k] = ldeg[k];
}

__global__ void make_dinv(const int* __restrict__ deg, float* dinv, int n) {
    int i = blockIdx.x * blockDim.x + threadIdx.x;
    if (i < n) dinv[i] = rsqrtf((float)deg[i] + 1.0f);  // +1 self-loop
}

// ---------------- exclusive scan of deg -> rowptr ----------------
__global__ void scan_blk(const int* __restrict__ deg, int* rowptr,
                         int* blksum, int n) {
    __shared__ int sh[1024];
    int tid = threadIdx.x;
    int g = blockIdx.x * 1024 + tid;
    int v = (g < n) ? deg[g] : 0;
    sh[tid] = v;
    __syncthreads();
    for (int off = 1; off < 1024; off <<= 1) {
        int t = (tid >= off) ? sh[tid - off] : 0;
        __syncthreads();
        sh[tid] += t;
        __syncthreads();
    }
    if (g < n) rowptr[g + 1] = sh[tid];
    if (tid == 1023) blksum[blockIdx.x] = sh[1023];
}

__global__ void scan_sums(int* blksum, int nb) {
    if (blockIdx.x == 0 && threadIdx.x == 0) {
        int run = 0;
        for (int b = 0; b < nb; ++b) { run += blksum[b]; blksum[b] = run; }
    }
}

__global__ void scan_add(int* rowptr, const int* __restrict__ blksum, int n) {
    int g = blockIdx.x * blockDim.x + threadIdx.x;
    if (g == 0) rowptr[0] = 0;
    if (g < n) {
        int b = g >> 10;
        if (b > 0) rowptr[g + 1] += blksum[b - 1];
    }
}

// ------- phase B: one block per bucket, scatter src into 12.5KB slice ---
__global__ void fillB(const unsigned* __restrict__ stage, const int* __restrict__ bcur,
                      const int* __restrict__ rowptr, int* __restrict__ csrs, int n) {
    __shared__ int lcur[256];
    int p = blockIdx.x;
    int lo = bucket_lo(p, n), hi = bucket_lo(p + 1, n);
    int nloc = hi - lo;
    for (int k = threadIdx.x; k < nloc; k += blockDim.x) lcur[k] = 0;
    __syncthreads();
    int s0 = p * BCAP, s1 = bcur[p];
    for (int i = s0 + threadIdx.x; i < s1; i += blockDim.x) {
        unsigned pk = stage[i];
        int ldst = (int)(pk & 255u);
        int pos = rowptr[lo + ldst] + atomicAdd(&lcur[ldst], 1);
        csrs[pos] = (int)(pk >> 8);
    }
}

// ---------------- layer-1 aggregate on raw x (5-dim), thread = node ------
__global__ void gather5(const int* __restrict__ rowptr,
                        const int* __restrict__ csrs,
                        const float* __restrict__ dinv,
                        const float* __restrict__ x,
                        float* __restrict__ z, int n) {
    int i = blockIdx.x * blockDim.x + threadIdx.x;
    if (i >= n) return;
    float di = dinv[i];
    float ws = di * di;
    const float* xr = x + (size_t)i * 5;
    float4 x4 = *(const float4*)(xr);
    float a0 = x4.x * ws, a1 = x4.y * ws, a2 = x4.z * ws,
          a3 = x4.w * ws, a4 = xr[4] * ws;
    int end = rowptr[i + 1];
    for (int j = rowptr[i]; j < end; ++j) {
        int s = csrs[j];
        float w = dinv[s] * di;
        const float* r = x + (size_t)s * 5;
        float4 r4 = *(const float4*)(r);
        float r1 = r[4];
        a0 = fmaf(w, r4.x, a0);
        a1 = fmaf(w, r4.y, a1);
        a2 = fmaf(w, r4.z, a2);
        a3 = fmaf(w, r4.w, a3);
        a4 = fmaf(w, r1, a4);
    }
    float* zr = z + (size_t)i * 5;
    zr[0] = a0; zr[1] = a1; zr[2] = a2; zr[3] = a3; zr[4] = a4;
}

// ---- transform epilogue: bias/relu/scale + fp32 or packed-bf16 store ----
template<int DOUT, bool BR, bool SCALE, bool OUTBF>
static __device__ __forceinline__ void emit(float o[8], const float* b, int c,
                                            float dsc, void* out, int i) {
    if (BR) {
        float4 b0 = *(const float4*)(b + c * 8);
        float4 b1 = *(const float4*)(b + c * 8 + 4);
        o[0] = fmaxf(o[0] + b0.x, 0.f); o[1] = fmaxf(o[1] + b0.y, 0.f);
        o[2] = fmaxf(o[2] + b0.z, 0.f); o[3] = fmaxf(o[3] + b0.w, 0.f);
        o[4] = fmaxf(o[4] + b1.x, 0.f); o[5] = fmaxf(o[5] + b1.y, 0.f);
        o[6] = fmaxf(o[6] + b1.z, 0.f); o[7] = fmaxf(o[7] + b1.w, 0.f);
    }
    if (SCALE) {
#pragma unroll
        for (int q = 0; q < 8; ++q) o[q] *= dsc;
    }
    if (OUTBF) {
        uint4 pk;
        pk.x = packbf(o[0], o[1]); pk.y = packbf(o[2], o[3]);
        pk.z = packbf(o[4], o[5]); pk.w = packbf(o[6], o[7]);
        *(uint4*)((unsigned*)out + (size_t)i * (DOUT / 2) + c * 4) = pk;
    } else {
        float* op = (float*)out + (size_t)i * DOUT + c * 8;
        float4 o0 = {o[0], o[1], o[2], o[3]};
        float4 o1 = {o[4], o[5], o[6], o[7]};
        *(float4*)(op) = o0;
        *(float4*)(op + 4) = o1;
    }
}

// ------- fp32-input dense transform, W staged in LDS ---------------------
// thread = (node-pair, 8-output chunk); W reads via ds_read_b128
template<int K, int DOUT, bool BR, bool SCALE, bool OUTBF, int NODES>
__global__ __launch_bounds__(256) void transformLDS(
        const float* __restrict__ xin,      // [n][K] fp32
        const float* __restrict__ W,        // [K][DOUT]
        const float* __restrict__ b,
        const float* __restrict__ dinv,
        void* __restrict__ out, int n) {
    __shared__ float wlds[K * DOUT];
    for (int t = threadIdx.x; t < K * DOUT / 4; t += blockDim.x)
        ((float4*)wlds)[t] = ((const float4*)W)[t];
    __syncthreads();
    const int C = DOUT / 8;
    int tid = blockIdx.x * blockDim.x + threadIdx.x;
    int grp = tid / C;
    int c = tid % C;
    int i0 = grp * NODES;
    if (i0 >= n) return;
    float acc[NODES][8];
#pragma unroll
    for (int nn = 0; nn < NODES; ++nn)
#pragma unroll
        for (int q = 0; q < 8; ++q) acc[nn][q] = 0.0f;

    static_assert(K % 8 == 0, "K multiple of 8");
    for (int k0 = 0; k0 < K; k0 += 8) {
        float4 r[NODES][2];
#pragma unroll
        for (int nn = 0; nn < NODES; ++nn) {
            int idx = i0 + nn < n ? i0 + nn : n - 1;
            const float4* rp = (const float4*)(xin + (size_t)idx * K + k0);
            r[nn][0] = rp[0];
            r[nn][1] = rp[1];
        }
#pragma unroll
        for (int kk = 0; kk < 8; ++kk) {
            const float* wp = wlds + (size_t)(k0 + kk) * DOUT + c * 8;
            float4 w0 = *(const float4*)(wp);      // ds_read_b128
            float4 w1 = *(const float4*)(wp + 4);
#pragma unroll
            for (int nn = 0; nn < NODES; ++nn) {
                float v = ((const float*)&r[nn][0])[kk];
                acc[nn][0] = fmaf(v, w0.x, acc[nn][0]);
                acc[nn][1] = fmaf(v, w0.y, acc[nn][1]);
                acc[nn][2] = fmaf(v, w0.z, acc[nn][2]);
                acc[nn][3] = fmaf(v, w0.w, acc[nn][3]);
                acc[nn][4] = fmaf(v, w1.x, acc[nn][4]);
                acc[nn][5] = fmaf(v, w1.y, acc[nn][5]);
                acc[nn][6] = fmaf(v, w1.z, acc[nn][6]);
                acc[nn][7] = fmaf(v, w1.w, acc[nn][7]);
            }
        }
    }
#pragma unroll
    for (int nn = 0; nn < NODES; ++nn) {
        if (i0 + nn >= n) break;
        float dsc = SCALE ? dinv[i0 + nn] : 1.0f;
        emit<DOUT, BR, SCALE, OUTBF>(acc[nn], b, c, dsc, out, i0 + nn);
    }
}

// ---- K=5 fp32-input variant (layer 1) ----------------------------------
template<int DOUT, bool BR, bool SCALE, bool OUTBF, int NODES>
__global__ void transformB5(const float* __restrict__ xin,
                            const float* __restrict__ W,
                            const float* __restrict__ b,
                            const float* __restrict__ dinv,
                            void* __restrict__ out, int n) {
    const int C = DOUT / 8;
    int tid = blockIdx.x * blockDim.x + threadIdx.x;
    int grp = tid / C;
    int c = tid % C;
    int i0 = grp * NODES;
    if (i0 >= n) return;
    float r[NODES][5];
#pragma unroll
    for (int nn = 0; nn < NODES; ++nn) {
        int idx = i0 + nn < n ? i0 + nn : n - 1;
        const float* row = xin + (size_t)idx * 5;
#pragma unroll
        for (int k = 0; k < 5; ++k) r[nn][k] = row[k];
    }
    float acc[NODES][8];
#pragma unroll
    for (int nn = 0; nn < NODES; ++nn)
#pragma unroll
        for (int q = 0; q < 8; ++q) acc[nn][q] = 0.0f;
#pragma unroll
    for (int k = 0; k < 5; ++k) {
        const float* wp = W + (size_t)k * DOUT + c * 8;
        float4 w0 = *(const float4*)(wp);
        float4 w1 = *(const float4*)(wp + 4);
#pragma unroll
        for (int nn = 0; nn < NODES; ++nn) {
            float v = r[nn][k];
            acc[nn][0] = fmaf(v, w0.x, acc[nn][0]);
            acc[nn][1] = fmaf(v, w0.y, acc[nn][1]);
            acc[nn][2] = fmaf(v, w0.z, acc[nn][2]);
            acc[nn][3] = fmaf(v, w0.w, acc[nn][3]);
            acc[nn][4] = fmaf(v, w1.x, acc[nn][4]);
            acc[nn][5] = fmaf(v, w1.y, acc[nn][5]);
            acc[nn][6] = fmaf(v, w1.z, acc[nn][6]);
            acc[nn][7] = fmaf(v, w1.w, acc[nn][7]);
        }
    }
#pragma unroll
    for (int nn = 0; nn < NODES; ++nn) {
        if (i0 + nn >= n) break;
        float dsc = SCALE ? dinv[i0 + nn] : 1.0f;
        emit<DOUT, BR, SCALE, OUTBF>(acc[nn], b, c, dsc, out, i0 + nn);
    }
}

// ------- 64-dim gather from bf16 table (dinv pre-folded into table) ------
// z[i] = dinv[i] * (g[i] + sum_src g[s]);   8 lanes/node, 8 feats/lane
template<bool BR>
__global__ void gatherBF(const int* __restrict__ rowptr,
                         const int* __restrict__ csrs,
                         const float* __restrict__ dinv,
                         const float* __restrict__ b,
                         const unsigned* __restrict__ g,   // [n][32] packed bf16
                         float* __restrict__ z, int n) {
    int tid = blockIdx.x * blockDim.x + threadIdx.x;
    int i = tid >> 3;
    int c = tid & 7;
    if (i >= n) return;
    uint4 sv = *(const uint4*)(g + (size_t)i * 32 + c * 4);
    float a0[8], a1[8];
    a0[0] = blo(sv.x); a0[1] = bhi(sv.x); a0[2] = blo(sv.y); a0[3] = bhi(sv.y);
    a0[4] = blo(sv.z); a0[5] = bhi(sv.z); a0[6] = blo(sv.w); a0[7] = bhi(sv.w);
#pragma unroll
    for (int q = 0; q < 8; ++q) a1[q] = 0.0f;
    int j = rowptr[i], end = rowptr[i + 1];
    for (; j + 1 < end; j += 2) {
        int s0 = csrs[j], s1 = csrs[j + 1];
        uint4 v0 = *(const uint4*)(g + (size_t)s0 * 32 + c * 4);
        uint4 v1 = *(const uint4*)(g + (size_t)s1 * 32 + c * 4);
        a0[0] += blo(v0.x); a0[1] += bhi(v0.x); a0[2] += blo(v0.y); a0[3] += bhi(v0.y);
        a0[4] += blo(v0.z); a0[5] += bhi(v0.z); a0[6] += blo(v0.w); a0[7] += bhi(v0.w);
        a1[0] += blo(v1.x); a1[1] += bhi(v1.x); a1[2] += blo(v1.y); a1[3] += bhi(v1.y);
        a1[4] += blo(v1.z); a1[5] += bhi(v1.z); a1[6] += blo(v1.w); a1[7] += bhi(v1.w);
    }
    if (j < end) {
        int s0 = csrs[j];
        uint4 v0 = *(const uint4*)(g + (size_t)s0 * 32 + c * 4);
        a0[0] += blo(v0.x); a0[1] += bhi(v0.x); a0[2] += blo(v0.y); a0[3] += bhi(v0.y);
        a0[4] += blo(v0.z); a0[5] += bhi(v0.z); a0[6] += blo(v0.w); a0[7] += bhi(v0.w);
    }
    float di = dinv[i];
    float o[8];
#pragma unroll
    for (int q = 0; q < 8; ++q) o[q] = di * (a0[q] + a1[q]);
    if (BR) {
        float4 b0 = *(const float4*)(b + c * 8);
        float4 b1 = *(const float4*)(b + c * 8 + 4);
        o[0] = fmaxf(o[0] + b0.x, 0.f); o[1] = fmaxf(o[1] + b0.y, 0.f);
        o[2] = fmaxf(o[2] + b0.z, 0.f); o[3] = fmaxf(o[3] + b0.w, 0.f);
        o[4] = fmaxf(o[4] + b1.x, 0.f); o[5] = fmaxf(o[5] + b1.y, 0.f);
        o[6] = fmaxf(o[6] + b1.z, 0.f); o[7] = fmaxf(o[7] + b1.w, 0.f);
    }
    float* zp = z + (size_t)i * 64 + c * 8;
    float4 z0 = {o[0], o[1], o[2], o[3]};
    float4 z1 = {o[4], o[5], o[6], o[7]};
    *(float4*)(zp) = z0;
    *(float4*)(zp + 4) = z1;
}

// ------- pooling + FC + sigmoid: 4 waves per graph, LDS combine ---------
__global__ void pool(const float* __restrict__ h3, const int* __restrict__ batch,
                     const float* __restrict__ Wfc, const float* __restrict__ bfc,
                     float* __restrict__ out, int n) {
    int g = blockIdx.x;
    int lane = threadIdx.x & 63;
    int w = threadIdx.x >> 6;  // 0..3
    int lo = 0, hi = n;
    while (lo < hi) { int m = (lo + hi) >> 1; if (batch[m] < g) lo = m + 1; else hi = m; }
    int start = lo;
    hi = n;
    while (lo < hi) { int m = (lo + hi) >> 1; if (batch[m] < g + 1) lo = m + 1; else hi = m; }
    int end = lo;
    float a0 = 0.f, a1 = 0.f, a2 = 0.f, a3 = 0.f;
    int m = start + w;
    for (; m + 12 < end; m += 16) {
        a0 += h3[(size_t)m * 64 + lane];
        a1 += h3[(size_t)(m + 4) * 64 + lane];
        a2 += h3[(size_t)(m + 8) * 64 + lane];
        a3 += h3[(size_t)(m + 12) * 64 + lane];
    }
    for (; m < end; m += 4) a0 += h3[(size_t)m * 64 + lane];
    __shared__ float sh[4][64];
    sh[w][lane] = (a0 + a1) + (a2 + a3);
    __syncthreads();
    if (w == 0) {
        float v = (sh[0][lane] + sh[1][lane]) + (sh[2][lane] + sh[3][lane]);
        float cnt = (float)(end - start);
        v = (v / fmaxf(cnt, 1.0f)) * Wfc[lane];
#pragma unroll
        for (int off = 32; off > 0; off >>= 1) v += __shfl_down(v, off, 64);
        if (lane == 0) out[g] = 1.0f / (1.0f + expf(-(v + bfc[0])));
    }
}

static inline int cdiv(long long a, int b) { return (int)((a + b - 1) / b); }

extern "C" void kernel_launch(void* const* d_in, const int* in_sizes, int n_in,
                              void* d_out, int out_size, void* d_ws, size_t ws_size,
                              hipStream_t stream) {
    const float* x   = (const float*)d_in[0];
    const int*   ei  = (const int*)d_in[1];
    const int*   bat = (const int*)d_in[2];
    const float* W1  = (const float*)d_in[3];
    const float* b1  = (const float*)d_in[4];
    const float* W2  = (const float*)d_in[5];
    const float* b2  = (const float*)d_in[6];
    const float* W3  = (const float*)d_in[7];
    const float* b3  = (const float*)d_in[8];
    const float* Wfc = (const float*)d_in[9];
    const float* bfc = (const float*)d_in[10];
    float* out = (float*)d_out;

    const int N = in_sizes[0] / 5;   // 100000
    const int E = in_sizes[1] / 2;   // 1600000
    const int* src = ei;
    const int* dst = ei + E;

    // ---- workspace layout ----
    float* ws     = (float*)d_ws;
    float* dinv   = ws;                          // N
    int*   deg    = (int*)(dinv + N);            // N
    int*   rowptr = deg + N;                     // N+4
    int*   blksum = rowptr + N + 4;              // 128
    int*   bcur   = blksum + 128;                // NBK
    int*   csrs   = bcur + NBK;                  // E (src only)
    float* A      = (float*)(csrs + E);          // N*128 floats
    float* B      = A + (size_t)N * 128;         // N*128 floats
    // aliases (strictly sequential lifetimes):
    unsigned* stage = (unsigned*)A;              // 7.3MB, dead after fillB
    float*    z1    = A;                         // N*5 fp32
    unsigned* h1bf  = (unsigned*)B;              // N*32 (bf16, dinv-folded)
    float*    z2    = A;                         // N*64 fp32 (z1 dead)
    float*    h2    = B;                         // N*128 fp32 (h1bf dead)
    unsigned* t3bf  = (unsigned*)A;              // N*32 bf16 (z2 dead)
    float*    h3    = B;                         // N*64 fp32 (h2 dead)

    const int Blk = 256;
    const int NB = cdiv(N, 1024);

    // ---- CSR build: bucket sort -> per-bucket hist -> scan -> fill ----
    zero_bcur<<<2, 256, 0, stream>>>(bcur);
    bucketA<<<256, 256, 0, stream>>>(src, dst, bcur, stage, E, N);
    histB<<<NBK, 256, 0, stream>>>(stage, bcur, deg, N);
    make_dinv<<<cdiv(N, Blk), Blk, 0, stream>>>(deg, dinv, N);
    scan_blk<<<NB, 1024, 0, stream>>>(deg, rowptr, blksum, N);
    scan_sums<<<1, 64, 0, stream>>>(blksum, NB);
    scan_add<<<cdiv(N, Blk), Blk, 0, stream>>>(rowptr, blksum, N);
    fillB<<<NBK, 256, 0, stream>>>(stage, bcur, rowptr, csrs, N);

    // ---- layer 1: aggregate raw x (5-dim); 5->64 +bias+relu ->bf16*dinv --
    gather5<<<cdiv(N, Blk), Blk, 0, stream>>>(rowptr, csrs, dinv, x, z1, N);
    transformB5<64, true, true, true, 2>
        <<<cdiv((long long)cdiv(N, 2) * 8, Blk), Blk, 0, stream>>>(
        z1, W1, b1, dinv, h1bf, N);

    // ---- layer 2: gather bf16 h1 -> z2 (fp32); 64->128 +bias+relu (fp32) --
    gatherBF<false><<<cdiv((long long)N * 8, Blk), Blk, 0, stream>>>(
        rowptr, csrs, dinv, nullptr, h1bf, z2, N);
    transformLDS<64, 128, true, false, false, 2>
        <<<cdiv((long long)cdiv(N, 2) * 16, Blk), Blk, 0, stream>>>(
        z2, W2, b2, nullptr, h2, N);

    // ---- layer 3: 128->64 ->bf16*dinv; gather +bias+relu -> fp32 h3 ----
    transformLDS<128, 64, false, true, true, 2>
        <<<cdiv((long long)cdiv(N, 2) * 8, Blk), Blk, 0, stream>>>(
        h2, W3, nullptr, dinv, t3bf, N);
    gatherBF<true><<<cdiv((long long)N * 8, Blk), Blk, 0, stream>>>(
        rowptr, csrs, dinv, b3, t3bf, h3, N);

    // ---- pooling + FC head ----
    pool<<<NG, 256, 0, stream>>>(h3, bat, Wfc, bfc, out, N);
}

// Round 10
// 403.511 us; speedup vs baseline: 1.5038x; 1.1145x over previous
//
#include <hip/hip_runtime.h>
#include <math.h>

#define NG 256
#define NBK 512          // sort buckets
#define BCAP 3584        // per-bucket staging capacity (mean 3125, +8 sigma)

static __device__ __forceinline__ int bucket_lo(int p, int n) {
    return (int)(((long long)p * n + NBK - 1) / NBK);   // ceil(p*n/NBK)
}

// ---- bf16 helpers (tables stored as packed pairs in uint) ----
static __device__ __forceinline__ float blo(unsigned u) {
    return __uint_as_float(u << 16);
}
static __device__ __forceinline__ float bhi(unsigned u) {
    return __uint_as_float(u & 0xFFFF0000u);
}
static __device__ __forceinline__ unsigned packbf(float a, float b) {
    unsigned ua = __float_as_uint(a);
    ua = (ua + 0x7FFFu + ((ua >> 16) & 1u)) >> 16;          // RNE, low half
    unsigned ub = __float_as_uint(b);
    ub = (ub + 0x7FFFu + ((ub >> 16) & 1u)) & 0xFFFF0000u;  // RNE, high half
    return ua | ub;
}

// ---------------- bucket cursor init ----------------
__global__ void zero_bcur(int* bcur) {
    int i = blockIdx.x * blockDim.x + threadIdx.x;
    if (i < NBK) bcur[i] = i * BCAP;
}

// ------- phase A: bucket edges by dst; staged record = (src<<8)|local_dst --
__global__ void bucketA(const int* __restrict__ src, const int* __restrict__ dst,
                        int* bcur, unsigned* stage, int e, int n) {
    __shared__ int cnt[NBK];
    __shared__ int base[NBK];
    int nb = gridDim.x;
    int c0 = (int)((long long)blockIdx.x * e / nb);
    int c1 = (int)((long long)(blockIdx.x + 1) * e / nb);
    for (int k = threadIdx.x; k < NBK; k += blockDim.x) cnt[k] = 0;
    __syncthreads();
    for (int i = c0 + threadIdx.x; i < c1; i += blockDim.x) {
        int d = dst[i];
        int p = (int)((long long)d * NBK / n);
        atomicAdd(&cnt[p], 1);
    }
    __syncthreads();
    for (int k = threadIdx.x; k < NBK; k += blockDim.x)
        base[k] = atomicAdd(&bcur[k], cnt[k]);
    __syncthreads();
    for (int k = threadIdx.x; k < NBK; k += blockDim.x) cnt[k] = 0;
    __syncthreads();
    for (int i = c0 + threadIdx.x; i < c1; i += blockDim.x) {
        int s = src[i], d = dst[i];
        int p = (int)((long long)d * NBK / n);
        int ldst = d - bucket_lo(p, n);           // < 196, fits 8 bits
        int lp = atomicAdd(&cnt[p], 1);
        stage[base[p] + lp] = ((unsigned)s << 8) | (unsigned)ldst;
    }
}

// ------- per-bucket degree histogram (LDS counters, coalesced write) ----
__global__ void histB(const unsigned* __restrict__ stage, const int* __restrict__ bcur,
                      int* __restrict__ deg, int n) {
    __shared__ int ldeg[256];
    int p = blockIdx.x;
    int lo = bucket_lo(p, n), hi = bucket_lo(p + 1, n);
    int nloc = hi - lo;
    for (int k = threadIdx.x; k < nloc; k += blockDim.x) ldeg[k] = 0;
    __syncthreads();
    int s0 = p * BCAP, s1 = bcur[p];
    for (int i = s0 + threadIdx.x; i < s1; i += blockDim.x)
        atomicAdd(&ldeg[stage[i] & 255u], 1);
    __syncthreads();
    for (int k = threadIdx.x; k < nloc; k += blockDim.x) deg[lo + k] = ldeg[k];
}

__global__ void make_dinv(const int* __restrict__ deg, float* dinv, int n) {
    int i = blockIdx.x * blockDim.x + threadIdx.x;
    if (i < n) dinv[i] = rsqrtf((float)deg[i] + 1.0f);  // +1 self-loop
}

// ---------------- exclusive scan of deg -> rowptr ----------------
__global__ void scan_blk(const int* __restrict__ deg, int* rowptr,
                         int* blksum, int n) {
    __shared__ int sh[1024];
    int tid = threadIdx.x;
    int g = blockIdx.x * 1024 + tid;
    int v = (g < n) ? deg[g] : 0;
    sh[tid] = v;
    __syncthreads();
    for (int off = 1; off < 1024; off <<= 1) {
        int t = (tid >= off) ? sh[tid - off] : 0;
        __syncthreads();
        sh[tid] += t;
        __syncthreads();
    }
    if (g < n) rowptr[g + 1] = sh[tid];
    if (tid == 1023) blksum[blockIdx.x] = sh[1023];
}

__global__ void scan_sums(int* blksum, int nb) {
    if (blockIdx.x == 0 && threadIdx.x == 0) {
        int run = 0;
        for (int b = 0; b < nb; ++b) { run += blksum[b]; blksum[b] = run; }
    }
}

__global__ void scan_add(int* rowptr, const int* __restrict__ blksum, int n) {
    int g = blockIdx.x * blockDim.x + threadIdx.x;
    if (g == 0) rowptr[0] = 0;
    if (g < n) {
        int b = g >> 10;
        if (b > 0) rowptr[g + 1] += blksum[b - 1];
    }
}

// ------- phase B: one block per bucket, scatter src into 12.5KB slice ---
__global__ void fillB(const unsigned* __restrict__ stage, const int* __restrict__ bcur,
                      const int* __restrict__ rowptr, int* __restrict__ csrs, int n) {
    __shared__ int lcur[256];
    int p = blockIdx.x;
    int lo = bucket_lo(p, n), hi = bucket_lo(p + 1, n);
    int nloc = hi - lo;
    for (int k = threadIdx.x; k < nloc; k += blockDim.x) lcur[k] = 0;
    __syncthreads();
    int s0 = p * BCAP, s1 = bcur[p];
    for (int i = s0 + threadIdx.x; i < s1; i += blockDim.x) {
        unsigned pk = stage[i];
        int ldst = (int)(pk & 255u);
        int pos = rowptr[lo + ldst] + atomicAdd(&lcur[ldst], 1);
        csrs[pos] = (int)(pk >> 8);
    }
}

// ---------------- layer-1 aggregate on raw x (5-dim), thread = node ------
__global__ void gather5(const int* __restrict__ rowptr,
                        const int* __restrict__ csrs,
                        const float* __restrict__ dinv,
                        const float* __restrict__ x,
                        float* __restrict__ z, int n) {
    int i = blockIdx.x * blockDim.x + threadIdx.x;
    if (i >= n) return;
    float di = dinv[i];
    float ws = di * di;
    const float* xr = x + (size_t)i * 5;
    float4 x4 = *(const float4*)(xr);
    float a0 = x4.x * ws, a1 = x4.y * ws, a2 = x4.z * ws,
          a3 = x4.w * ws, a4 = xr[4] * ws;
    int end = rowptr[i + 1];
    for (int j = rowptr[i]; j < end; ++j) {
        int s = csrs[j];
        float w = dinv[s] * di;
        const float* r = x + (size_t)s * 5;
        float4 r4 = *(const float4*)(r);
        float r1 = r[4];
        a0 = fmaf(w, r4.x, a0);
        a1 = fmaf(w, r4.y, a1);
        a2 = fmaf(w, r4.z, a2);
        a3 = fmaf(w, r4.w, a3);
        a4 = fmaf(w, r1, a4);
    }
    float* zr = z + (size_t)i * 5;
    zr[0] = a0; zr[1] = a1; zr[2] = a2; zr[3] = a3; zr[4] = a4;
}

// ---- transform epilogue: bias/relu/scale + fp32 or packed-bf16 store ----
template<int DOUT, bool BR, bool SCALE, bool OUTBF>
static __device__ __forceinline__ void emit(float o[8], const float* b, int c,
                                            float dsc, void* out, int i) {
    if (BR) {
        float4 b0 = *(const float4*)(b + c * 8);
        float4 b1 = *(const float4*)(b + c * 8 + 4);
        o[0] = fmaxf(o[0] + b0.x, 0.f); o[1] = fmaxf(o[1] + b0.y, 0.f);
        o[2] = fmaxf(o[2] + b0.z, 0.f); o[3] = fmaxf(o[3] + b0.w, 0.f);
        o[4] = fmaxf(o[4] + b1.x, 0.f); o[5] = fmaxf(o[5] + b1.y, 0.f);
        o[6] = fmaxf(o[6] + b1.z, 0.f); o[7] = fmaxf(o[7] + b1.w, 0.f);
    }
    if (SCALE) {
#pragma unroll
        for (int q = 0; q < 8; ++q) o[q] *= dsc;
    }
    if (OUTBF) {
        uint4 pk;
        pk.x = packbf(o[0], o[1]); pk.y = packbf(o[2], o[3]);
        pk.z = packbf(o[4], o[5]); pk.w = packbf(o[6], o[7]);
        *(uint4*)((unsigned*)out + (size_t)i * (DOUT / 2) + c * 4) = pk;
    } else {
        float* op = (float*)out + (size_t)i * DOUT + c * 8;
        float4 o0 = {o[0], o[1], o[2], o[3]};
        float4 o1 = {o[4], o[5], o[6], o[7]};
        *(float4*)(op) = o0;
        *(float4*)(op + 4) = o1;
    }
}

// ------- dense transform, 8 outputs x NODES nodes per thread -------------
// global W float4 loads (L1/L2-hot), reused across NODES nodes
template<int K, int DOUT, bool BR, bool SCALE, bool OUTBF, int NODES>
__global__ void transformB(const float* __restrict__ xin,
                           const float* __restrict__ W,
                           const float* __restrict__ b,
                           const float* __restrict__ dinv,
                           void* __restrict__ out, int n) {
    const int C = DOUT / 8;
    int tid = blockIdx.x * blockDim.x + threadIdx.x;
    int grp = tid / C;
    int c = tid % C;
    int i0 = grp * NODES;
    if (i0 >= n) return;
    float acc[NODES][8];
#pragma unroll
    for (int nn = 0; nn < NODES; ++nn)
#pragma unroll
        for (int q = 0; q < 8; ++q) acc[nn][q] = 0.0f;

    static_assert(K % 4 == 0, "K multiple of 4");
    for (int k0 = 0; k0 < K; k0 += 4) {
        float4 r[NODES];
#pragma unroll
        for (int nn = 0; nn < NODES; ++nn) {
            int idx = i0 + nn < n ? i0 + nn : n - 1;
            r[nn] = *(const float4*)(xin + (size_t)idx * K + k0);
        }
#pragma unroll
        for (int kk = 0; kk < 4; ++kk) {
            const float* wp = W + (size_t)(k0 + kk) * DOUT + c * 8;
            float4 w0 = *(const float4*)(wp);
            float4 w1 = *(const float4*)(wp + 4);
#pragma unroll
            for (int nn = 0; nn < NODES; ++nn) {
                float v = (&r[nn].x)[kk];
                acc[nn][0] = fmaf(v, w0.x, acc[nn][0]);
                acc[nn][1] = fmaf(v, w0.y, acc[nn][1]);
                acc[nn][2] = fmaf(v, w0.z, acc[nn][2]);
                acc[nn][3] = fmaf(v, w0.w, acc[nn][3]);
                acc[nn][4] = fmaf(v, w1.x, acc[nn][4]);
                acc[nn][5] = fmaf(v, w1.y, acc[nn][5]);
                acc[nn][6] = fmaf(v, w1.z, acc[nn][6]);
                acc[nn][7] = fmaf(v, w1.w, acc[nn][7]);
            }
        }
    }
#pragma unroll
    for (int nn = 0; nn < NODES; ++nn) {
        if (i0 + nn >= n) break;
        float dsc = SCALE ? dinv[i0 + nn] : 1.0f;
        emit<DOUT, BR, SCALE, OUTBF>(acc[nn], b, c, dsc, out, i0 + nn);
    }
}

// ---- K=5 fp32-input variant (layer 1) ----------------------------------
template<int DOUT, bool BR, bool SCALE, bool OUTBF, int NODES>
__global__ void transformB5(const float* __restrict__ xin,
                            const float* __restrict__ W,
                            const float* __restrict__ b,
                            const float* __restrict__ dinv,
                            void* __restrict__ out, int n) {
    const int C = DOUT / 8;
    int tid = blockIdx.x * blockDim.x + threadIdx.x;
    int grp = tid / C;
    int c = tid % C;
    int i0 = grp * NODES;
    if (i0 >= n) return;
    float r[NODES][5];
#pragma unroll
    for (int nn = 0; nn < NODES; ++nn) {
        int idx = i0 + nn < n ? i0 + nn : n - 1;
        const float* row = xin + (size_t)idx * 5;
#pragma unroll
        for (int k = 0; k < 5; ++k) r[nn][k] = row[k];
    }
    float acc[NODES][8];
#pragma unroll
    for (int nn = 0; nn < NODES; ++nn)
#pragma unroll
        for (int q = 0; q < 8; ++q) acc[nn][q] = 0.0f;
#pragma unroll
    for (int k = 0; k < 5; ++k) {
        const float* wp = W + (size_t)k * DOUT + c * 8;
        float4 w0 = *(const float4*)(wp);
        float4 w1 = *(const float4*)(wp + 4);
#pragma unroll
        for (int nn = 0; nn < NODES; ++nn) {
            float v = r[nn][k];
            acc[nn][0] = fmaf(v, w0.x, acc[nn][0]);
            acc[nn][1] = fmaf(v, w0.y, acc[nn][1]);
            acc[nn][2] = fmaf(v, w0.z, acc[nn][2]);
            acc[nn][3] = fmaf(v, w0.w, acc[nn][3]);
            acc[nn][4] = fmaf(v, w1.x, acc[nn][4]);
            acc[nn][5] = fmaf(v, w1.y, acc[nn][5]);
            acc[nn][6] = fmaf(v, w1.z, acc[nn][6]);
            acc[nn][7] = fmaf(v, w1.w, acc[nn][7]);
        }
    }
#pragma unroll
    for (int nn = 0; nn < NODES; ++nn) {
        if (i0 + nn >= n) break;
        float dsc = SCALE ? dinv[i0 + nn] : 1.0f;
        emit<DOUT, BR, SCALE, OUTBF>(acc[nn], b, c, dsc, out, i0 + nn);
    }
}

// ------- 64-dim gather from bf16 table (dinv pre-folded into table) ------
// z[i] = dinv[i] * (g[i] + sum_src g[s]);   8 lanes/node, 8 feats/lane
template<bool BR>
__global__ void gatherBF(const int* __restrict__ rowptr,
                         const int* __restrict__ csrs,
                         const float* __restrict__ dinv,
                         const float* __restrict__ b,
                         const unsigned* __restrict__ g,   // [n][32] packed bf16
                         float* __restrict__ z, int n) {
    int tid = blockIdx.x * blockDim.x + threadIdx.x;
    int i = tid >> 3;
    int c = tid & 7;
    if (i >= n) return;
    uint4 sv = *(const uint4*)(g + (size_t)i * 32 + c * 4);
    float a0[8], a1[8];
    a0[0] = blo(sv.x); a0[1] = bhi(sv.x); a0[2] = blo(sv.y); a0[3] = bhi(sv.y);
    a0[4] = blo(sv.z); a0[5] = bhi(sv.z); a0[6] = blo(sv.w); a0[7] = bhi(sv.w);
#pragma unroll
    for (int q = 0; q < 8; ++q) a1[q] = 0.0f;
    int j = rowptr[i], end = rowptr[i + 1];
    for (; j + 1 < end; j += 2) {
        int s0 = csrs[j], s1 = csrs[j + 1];
        uint4 v0 = *(const uint4*)(g + (size_t)s0 * 32 + c * 4);
        uint4 v1 = *(const uint4*)(g + (size_t)s1 * 32 + c * 4);
        a0[0] += blo(v0.x); a0[1] += bhi(v0.x); a0[2] += blo(v0.y); a0[3] += bhi(v0.y);
        a0[4] += blo(v0.z); a0[5] += bhi(v0.z); a0[6] += blo(v0.w); a0[7] += bhi(v0.w);
        a1[0] += blo(v1.x); a1[1] += bhi(v1.x); a1[2] += blo(v1.y); a1[3] += bhi(v1.y);
        a1[4] += blo(v1.z); a1[5] += bhi(v1.z); a1[6] += blo(v1.w); a1[7] += bhi(v1.w);
    }
    if (j < end) {
        int s0 = csrs[j];
        uint4 v0 = *(const uint4*)(g + (size_t)s0 * 32 + c * 4);
        a0[0] += blo(v0.x); a0[1] += bhi(v0.x); a0[2] += blo(v0.y); a0[3] += bhi(v0.y);
        a0[4] += blo(v0.z); a0[5] += bhi(v0.z); a0[6] += blo(v0.w); a0[7] += bhi(v0.w);
    }
    float di = dinv[i];
    float o[8];
#pragma unroll
    for (int q = 0; q < 8; ++q) o[q] = di * (a0[q] + a1[q]);
    if (BR) {
        float4 b0 = *(const float4*)(b + c * 8);
        float4 b1 = *(const float4*)(b + c * 8 + 4);
        o[0] = fmaxf(o[0] + b0.x, 0.f); o[1] = fmaxf(o[1] + b0.y, 0.f);
        o[2] = fmaxf(o[2] + b0.z, 0.f); o[3] = fmaxf(o[3] + b0.w, 0.f);
        o[4] = fmaxf(o[4] + b1.x, 0.f); o[5] = fmaxf(o[5] + b1.y, 0.f);
        o[6] = fmaxf(o[6] + b1.z, 0.f); o[7] = fmaxf(o[7] + b1.w, 0.f);
    }
    float* zp = z + (size_t)i * 64 + c * 8;
    float4 z0 = {o[0], o[1], o[2], o[3]};
    float4 z1 = {o[4], o[5], o[6], o[7]};
    *(float4*)(zp) = z0;
    *(float4*)(zp + 4) = z1;
}

// ------- pooling + FC + sigmoid: 4 waves per graph, LDS combine ---------
__global__ void pool(const float* __restrict__ h3, const int* __restrict__ batch,
                     const float* __restrict__ Wfc, const float* __restrict__ bfc,
                     float* __restrict__ out, int n) {
    int g = blockIdx.x;
    int lane = threadIdx.x & 63;
    int w = threadIdx.x >> 6;  // 0..3
    int lo = 0, hi = n;
    while (lo < hi) { int m = (lo + hi) >> 1; if (batch[m] < g) lo = m + 1; else hi = m; }
    int start = lo;
    hi = n;
    while (lo < hi) { int m = (lo + hi) >> 1; if (batch[m] < g + 1) lo = m + 1; else hi = m; }
    int end = lo;
    float a0 = 0.f, a1 = 0.f, a2 = 0.f, a3 = 0.f;
    int m = start + w;
    for (; m + 12 < end; m += 16) {
        a0 += h3[(size_t)m * 64 + lane];
        a1 += h3[(size_t)(m + 4) * 64 + lane];
        a2 += h3[(size_t)(m + 8) * 64 + lane];
        a3 += h3[(size_t)(m + 12) * 64 + lane];
    }
    for (; m < end; m += 4) a0 += h3[(size_t)m * 64 + lane];
    __shared__ float sh[4][64];
    sh[w][lane] = (a0 + a1) + (a2 + a3);
    __syncthreads();
    if (w == 0) {
        float v = (sh[0][lane] + sh[1][lane]) + (sh[2][lane] + sh[3][lane]);
        float cnt = (float)(end - start);
        v = (v / fmaxf(cnt, 1.0f)) * Wfc[lane];
#pragma unroll
        for (int off = 32; off > 0; off >>= 1) v += __shfl_down(v, off, 64);
        if (lane == 0) out[g] = 1.0f / (1.0f + expf(-(v + bfc[0])));
    }
}

static inline int cdiv(long long a, int b) { return (int)((a + b - 1) / b); }

extern "C" void kernel_launch(void* const* d_in, const int* in_sizes, int n_in,
                              void* d_out, int out_size, void* d_ws, size_t ws_size,
                              hipStream_t stream) {
    const float* x   = (const float*)d_in[0];
    const int*   ei  = (const int*)d_in[1];
    const int*   bat = (const int*)d_in[2];
    const float* W1  = (const float*)d_in[3];
    const float* b1  = (const float*)d_in[4];
    const float* W2  = (const float*)d_in[5];
    const float* b2  = (const float*)d_in[6];
    const float* W3  = (const float*)d_in[7];
    const float* b3  = (const float*)d_in[8];
    const float* Wfc = (const float*)d_in[9];
    const float* bfc = (const float*)d_in[10];
    float* out = (float*)d_out;

    const int N = in_sizes[0] / 5;   // 100000
    const int E = in_sizes[1] / 2;   // 1600000
    const int* src = ei;
    const int* dst = ei + E;

    // ---- workspace layout ----
    float* ws     = (float*)d_ws;
    float* dinv   = ws;                          // N
    int*   deg    = (int*)(dinv + N);            // N
    int*   rowptr = deg + N;                     // N+4
    int*   blksum = rowptr + N + 4;              // 128
    int*   bcur   = blksum + 128;                // NBK
    int*   csrs   = bcur + NBK;                  // E (src only)
    float* A      = (float*)(csrs + E);          // N*128 floats
    float* B      = A + (size_t)N * 128;         // N*128 floats
    // aliases (strictly sequential lifetimes):
    unsigned* stage = (unsigned*)A;              // 7.3MB, dead after fillB
    float*    z1    = A;                         // N*5 fp32
    unsigned* h1bf  = (unsigned*)B;              // N*32 (bf16, dinv-folded)
    float*    z2    = A;                         // N*64 fp32 (z1 dead)
    float*    h2    = B;                         // N*128 fp32 (h1bf dead)
    unsigned* t3bf  = (unsigned*)A;              // N*32 bf16 (z2 dead)
    float*    h3    = B;                         // N*64 fp32 (h2 dead)

    const int Blk = 256;
    const int NB = cdiv(N, 1024);

    // ---- CSR build: bucket sort -> per-bucket hist -> scan -> fill ----
    zero_bcur<<<2, 256, 0, stream>>>(bcur);
    bucketA<<<256, 256, 0, stream>>>(src, dst, bcur, stage, E, N);
    histB<<<NBK, 256, 0, stream>>>(stage, bcur, deg, N);
    make_dinv<<<cdiv(N, Blk), Blk, 0, stream>>>(deg, dinv, N);
    scan_blk<<<NB, 1024, 0, stream>>>(deg, rowptr, blksum, N);
    scan_sums<<<1, 64, 0, stream>>>(blksum, NB);
    scan_add<<<cdiv(N, Blk), Blk, 0, stream>>>(rowptr, blksum, N);
    fillB<<<NBK, 256, 0, stream>>>(stage, bcur, rowptr, csrs, N);

    // ---- layer 1: aggregate raw x (5-dim); 5->64 +bias+relu ->bf16*dinv --
    gather5<<<cdiv(N, Blk), Blk, 0, stream>>>(rowptr, csrs, dinv, x, z1, N);
    transformB5<64, true, true, true, 2>
        <<<cdiv((long long)cdiv(N, 2) * 8, Blk), Blk, 0, stream>>>(
        z1, W1, b1, dinv, h1bf, N);

    // ---- layer 2: gather bf16 h1 -> z2 (fp32); 64->128 +bias+relu (fp32) --
    gatherBF<false><<<cdiv((long long)N * 8, Blk), Blk, 0, stream>>>(
        rowptr, csrs, dinv, nullptr, h1bf, z2, N);
    transformB<64, 128, true, false, false, 4>
        <<<cdiv((long long)cdiv(N, 4) * 16, Blk), Blk, 0, stream>>>(
        z2, W2, b2, nullptr, h2, N);

    // ---- layer 3: 128->64 ->bf16*dinv; gather +bias+relu -> fp32 h3 ----
    transformB<128, 64, false, true, true, 4>
        <<<cdiv((long long)cdiv(N, 4) * 8, Blk), Blk, 0, stream>>>(
        h2, W3, nullptr, dinv, t3bf, N);
    gatherBF<true><<<cdiv((long long)N * 8, Blk), Blk, 0, stream>>>(
        rowptr, csrs, dinv, b3, t3bf, h3, N);

    // ---- pooling + FC head ----
    pool<<<NG, 256, 0, stream>>>(h3, bat, Wfc, bfc, out, N);
}